// Round 5
// baseline (2383.328 us; speedup 1.0000x reference)
//
#include <hip/hip_runtime.h>

// LSTMCharacterPredictor — round 5: sentinel poll + atomic publish.
// T=512 B=64 E=512 H=1024 V=256.
// R4 post-mortem: tagged-data poll == flag poll (2110 vs 2136 us) -> the
// 3-round-trip model was wrong; transport itself is the cost. Fixes:
// (1) sentinel poll: 8 dwords/lane/round (was 64) -> 8x less poll BW, round
//     length ~= pure flight; full load + exact verify only after pass.
// (2) publish via global_atomic_swap: executes at coherence point, no lazy
//     write-buffer visibility.
// (3) proj packed [V][j][u][gate] f32: one dwordx4 prefetch per thread.

#define TT 512
#define BB 64
#define HH 1024
#define VV 256
#define EE 512

typedef __attribute__((ext_vector_type(8))) short bf16x8;
typedef __attribute__((ext_vector_type(4))) float f32x4;
typedef __attribute__((ext_vector_type(4))) int i32x4;
typedef __attribute__((ext_vector_type(4))) unsigned short u16x4;

static __device__ __forceinline__ unsigned short f2bf(float f) {
  union { float f; unsigned u; } x; x.f = f;
  unsigned r = x.u + 0x7fffu + ((x.u >> 16) & 1u);   // RNE
  return (unsigned short)(r >> 16);
}

// ---------------- f32 -> bf16 convert (vectorized) ----------------
__global__ void cvt_bf16(const float* __restrict__ s, unsigned short* __restrict__ d, int n4) {
  int i = blockIdx.x * blockDim.x + threadIdx.x;
  int st = gridDim.x * blockDim.x;
  for (; i < n4; i += st) {
    f32x4 v = *(const f32x4*)(s + 4l * i);
    u16x4 o;
    o.x = f2bf(v.x); o.y = f2bf(v.y); o.z = f2bf(v.z); o.w = f2bf(v.w);
    *(u16x4*)(d + 4l * i) = o;
  }
}

// ------- proj packed: proj[v][j][u][gate] = enc@W_ih^T + b_ih + b_hh -------
__global__ __launch_bounds__(256) void proj_kernel(
    const unsigned short* __restrict__ A,    // enc bf16 [256][512]
    const unsigned short* __restrict__ Wi,   // W_ih bf16 [4096][512]
    const float* __restrict__ bih, const float* __restrict__ bhh,
    float* __restrict__ proj)                // [256][64][16][4] f32
{
  __shared__ __align__(16) unsigned char Asm[64 * 128];   // [64 m][64 k] bf16, swizzled
  const int tid = threadIdx.x;
  const int w = tid >> 6;
  const int lane = tid & 63;
  const int ln = lane & 15, kg = lane >> 4;
  const int m0 = blockIdx.x * 64;            // 4 blocks
  const int nb = blockIdx.y * 256 + w * 64;  // 16 blocks.y, wave owns 64 n
  const int srow = tid >> 2, skq = tid & 3;

  f32x4 acc[4][4];
  for (int a = 0; a < 4; ++a) for (int b = 0; b < 4; ++b) acc[a][b] = (f32x4){0.f,0.f,0.f,0.f};

  for (int kc = 0; kc < 8; ++kc) {           // K=512 in chunks of 64
    {
      const unsigned short* src = A + (m0 + srow) * 512 + kc * 64 + skq * 16;
      unsigned base = (unsigned)(srow * 128 + skq * 32);
      unsigned sw = (unsigned)((srow & 7) << 4);
      *(i32x4*)(Asm + ((base) ^ sw))      = *(const i32x4*)(src);
      *(i32x4*)(Asm + ((base + 16) ^ sw)) = *(const i32x4*)(src + 8);
    }
    __syncthreads();
    for (int kk = 0; kk < 2; ++kk) {
      bf16x8 afr[4];
      for (int mi = 0; mi < 4; ++mi) {
        int row = mi * 16 + ln;
        unsigned off = (unsigned)(row * 128 + (kk * 32 + kg * 8) * 2);
        afr[mi] = *(const bf16x8*)(Asm + (off ^ ((unsigned)(row & 7) << 4)));
      }
      for (int ni = 0; ni < 4; ++ni) {
        const unsigned short* bp = Wi + (nb + ni * 16 + ln) * 512 + kc * 64 + kk * 32 + kg * 8;
        bf16x8 bfr = *(const bf16x8*)bp;
        for (int mi = 0; mi < 4; ++mi)
          acc[mi][ni] = __builtin_amdgcn_mfma_f32_16x16x32_bf16(afr[mi], bfr, acc[mi][ni], 0, 0, 0);
      }
    }
    __syncthreads();
  }
  for (int ni = 0; ni < 4; ++ni) {
    int nn = nb + ni * 16 + ln;             // global gate-row = gi*1024 + unit
    int gi = nn >> 10, uu = nn & 1023;
    float bias = bih[nn] + bhh[nn];
    for (int mi = 0; mi < 4; ++mi) {
      int mr = m0 + mi * 16 + kg * 4;
      for (int r = 0; r < 4; ++r)
        proj[(size_t)(mr + r) * 4096 + (uu >> 4) * 64 + (uu & 15) * 4 + gi]
            = acc[mi][ni][r] + bias;
    }
  }
}

// ---------------- persistent LSTM scan (tagged-h, sentinel poll) ----------------
// 256 blocks x 256 thr. group g=blk>>6 owns batches [g*16,+16); block j=blk&63
// owns hidden units [j*16,+16). Wave w holds W_hh B-frags for 4 gates over
// K-slice [w*256,+256) in VGPRs. hcomm[slot][b][u] = (bf16 h)<<16 | version,
// slot = version&1. Publish = global_atomic_swap (immediate at coherence pt).
// Consumer: sentinel-poll 8 dwords/lane (one per producer run), then full
// 16-vec4 load + exact-verify all 64 tags (retry on mismatch).
#define SPIN_CAP 32768

__global__ __launch_bounds__(256, 1) void scan_kernel(
    const unsigned short* __restrict__ Whh,   // bf16 [4096][1024]
    const float* __restrict__ proj,           // [256][64][16][4] f32 packed
    const int* __restrict__ ints,             // [512][64]
    const float* __restrict__ h0v,            // output0 [1024]
    const float* __restrict__ c0v,            // memory0 [1024]
    unsigned int* __restrict__ hcomm,         // [2][64][1024] tagged u32
    unsigned short* __restrict__ outs)        // bf16 [512][64][1024] h history
{
  __shared__ float gatesm[4][4][16][16];      // [w][gi][b][u] f32 partials (16 KB)

  const int tid = threadIdx.x;
  const int blk = blockIdx.x;
  const int g = blk >> 6, j = blk & 63;
  const int w = tid >> 6, lane = tid & 63;
  const int ln = lane & 15, kg = lane >> 4;
  const int b = tid >> 4, u = tid & 15;
  const int uglob = j * 16 + u;
  const int bglob = g * 16 + b;

  // W_hh B-fragments in registers: gate gi row (gi*1024 + j*16 + ln),
  // k = w*256 + kt*32 + kg*8 .. +8  (same k order as A-frags -> consistent).
  bf16x8 bw[4][8];
#pragma unroll
  for (int gi = 0; gi < 4; ++gi)
#pragma unroll
    for (int kt = 0; kt < 8; ++kt)
      bw[gi][kt] = *(const bf16x8*)(Whh + (size_t)(gi * 1024 + j * 16 + ln) * 1024
                                        + w * 256 + kt * 32 + kg * 8);

  float c = c0v[uglob];

  // publish version 1 (= h0) into slot 1 (atomic: immediate visibility)
  {
    float hv0 = h0v[uglob];
    unsigned short hb = f2bf(hv0);
    unsigned word = ((unsigned)hb << 16) | 1u;
    unsigned* hp = hcomm + 65536 + (size_t)bglob * 1024 + uglob;   // slot 1
    asm volatile("global_atomic_swap %0, %1, off" :: "v"(hp), "v"(word) : "memory");
    outs[(size_t)bglob * 1024 + uglob] = hb;
  }

  for (int t = 0; t < TT - 1; ++t) {
    // ---- prefetch packed proj row (1 dwordx4/thread; waits fold into poll) ----
    int vocab = ints[t * 64 + bglob];
    f32x4 prv;
    {
      const float* pp = proj + (size_t)vocab * 4096 + j * 64 + u * 4;
      asm volatile("global_load_dwordx4 %0, %1, off" : "=v"(prv) : "v"(pp) : "memory");
    }

    // ---- poll: sentinel (8 dw/lane) then full load + exact verify ----
    const unsigned* ab = hcomm + ((size_t)((t + 1) & 1)) * 65536
                       + (size_t)(g * 16 + ln) * 1024 + w * 256 + kg * 8;
    unsigned tgt = (unsigned)(t + 1);
    i32x4 q[16];
    {
      int guard = 0;
      bool ok = false;
      while (!ok) {
        // sentinel spin: last dword of each 8-word producer run
        while (true) {
          unsigned s0, s1, s2, s3, s4, s5, s6, s7;
#define LS(v, off_lit) \
          asm volatile("global_load_dword %0, %1, off offset:" off_lit " sc0 sc1" \
                       : "=v"(v) : "v"(ab) : "memory")
          LS(s0, "28");  LS(s1, "156"); LS(s2, "284"); LS(s3, "412");
          LS(s4, "540"); LS(s5, "668"); LS(s6, "796"); LS(s7, "924");
#undef LS
          asm volatile("s_waitcnt vmcnt(0)" ::: "memory");
          __builtin_amdgcn_sched_barrier(0);
          unsigned sb = (s0 ^ tgt) | (s1 ^ tgt) | (s2 ^ tgt) | (s3 ^ tgt)
                      | (s4 ^ tgt) | (s5 ^ tgt) | (s6 ^ tgt) | (s7 ^ tgt);
          if (__all((sb & 0xffffu) == 0u)) break;
          if (++guard > SPIN_CAP) break;      // deadlock escape (never legit)
        }
        // full load + exact verify (authority; retries on rare store skew)
#define LQ(i, off_lit) \
        asm volatile("global_load_dwordx4 %0, %1, off offset:" off_lit " sc0 sc1" \
                     : "=v"(q[i]) : "v"(ab) : "memory")
        LQ(0, "0");    LQ(1, "16");   LQ(2, "128");  LQ(3, "144");
        LQ(4, "256");  LQ(5, "272");  LQ(6, "384");  LQ(7, "400");
        LQ(8, "512");  LQ(9, "528");  LQ(10, "640"); LQ(11, "656");
        LQ(12, "768"); LQ(13, "784"); LQ(14, "896"); LQ(15, "912");
#undef LQ
        asm volatile("s_waitcnt vmcnt(0)" ::: "memory");
        __builtin_amdgcn_sched_barrier(0);
        unsigned bad = 0;
#pragma unroll
        for (int i = 0; i < 16; ++i) {
          bad |= ((unsigned)q[i].x ^ tgt);
          bad |= ((unsigned)q[i].y ^ tgt);
          bad |= ((unsigned)q[i].z ^ tgt);
          bad |= ((unsigned)q[i].w ^ tgt);
        }
        ok = __all((bad & 0xffffu) == 0u);
        if (guard > SPIN_CAP) break;
      }
    }
    __builtin_amdgcn_sched_barrier(0);

    // ---- strip tags, pack bf16x8 A-frags ----
    bf16x8 av[8];
#pragma unroll
    for (int kt = 0; kt < 8; ++kt) {
      i32x4 lo = q[2 * kt], hi = q[2 * kt + 1];
      unsigned d0 = ((unsigned)lo.x >> 16) | ((unsigned)lo.y & 0xffff0000u);
      unsigned d1 = ((unsigned)lo.z >> 16) | ((unsigned)lo.w & 0xffff0000u);
      unsigned d2 = ((unsigned)hi.x >> 16) | ((unsigned)hi.y & 0xffff0000u);
      unsigned d3 = ((unsigned)hi.z >> 16) | ((unsigned)hi.w & 0xffff0000u);
      union { i32x4 i; bf16x8 h; } u2;
      u2.i = (i32x4){ (int)d0, (int)d1, (int)d2, (int)d3 };
      av[kt] = u2.h;
    }

    // ---- 32 MFMAs, 4 independent chains (one per gate) ----
    f32x4 ac0 = (f32x4){0.f,0.f,0.f,0.f}, ac1 = ac0, ac2 = ac0, ac3 = ac0;
#pragma unroll
    for (int kt = 0; kt < 8; ++kt) {
      ac0 = __builtin_amdgcn_mfma_f32_16x16x32_bf16(av[kt], bw[0][kt], ac0, 0, 0, 0);
      ac1 = __builtin_amdgcn_mfma_f32_16x16x32_bf16(av[kt], bw[1][kt], ac1, 0, 0, 0);
      ac2 = __builtin_amdgcn_mfma_f32_16x16x32_bf16(av[kt], bw[2][kt], ac2, 0, 0, 0);
      ac3 = __builtin_amdgcn_mfma_f32_16x16x32_bf16(av[kt], bw[3][kt], ac3, 0, 0, 0);
    }

    // ---- cross-wave K-reduction via LDS ----
    // D layout: n(unit)=lane&15, m(batch)=(lane>>4)*4+r  [m89-verified]
#pragma unroll
    for (int r = 0; r < 4; ++r) {
      gatesm[w][0][kg * 4 + r][ln] = ac0[r];
      gatesm[w][1][kg * 4 + r][ln] = ac1[r];
      gatesm[w][2][kg * 4 + r][ln] = ac2[r];
      gatesm[w][3][kg * 4 + r][ln] = ac3[r];
    }
    __syncthreads();

    // ---- elementwise cell update: thread (b,u) ----
    float gi_ = prv.x, gf_ = prv.y, gg_ = prv.z, go_ = prv.w;
#pragma unroll
    for (int ww = 0; ww < 4; ++ww) {
      gi_ += gatesm[ww][0][b][u];
      gf_ += gatesm[ww][1][b][u];
      gg_ += gatesm[ww][2][b][u];
      go_ += gatesm[ww][3][b][u];
    }
    float ii = __builtin_amdgcn_rcpf(1.f + __expf(-gi_));
    float ff = __builtin_amdgcn_rcpf(1.f + __expf(-gf_));
    float gt = 1.f - 2.f * __builtin_amdgcn_rcpf(1.f + __expf(2.f * gg_));
    float oo = __builtin_amdgcn_rcpf(1.f + __expf(-go_));
    c = ff * c + ii * gt;
    float hv = oo * (1.f - 2.f * __builtin_amdgcn_rcpf(1.f + __expf(2.f * c)));

    // ---- publish version t+2 (atomic, immediate) + outs[t+1] ----
    {
      unsigned short hb = f2bf(hv);
      unsigned word = ((unsigned)hb << 16) | ((unsigned)(t + 2) & 0xffffu);
      unsigned* hp = hcomm + ((size_t)((t + 2) & 1)) * 65536
                   + (size_t)bglob * 1024 + uglob;
      asm volatile("global_atomic_swap %0, %1, off" :: "v"(hp), "v"(word) : "memory");
      outs[(size_t)(t + 1) * 65536 + (size_t)bglob * 1024 + uglob] = hb;
    }
    // WAR guard for gatesm across steps.
    __syncthreads();
  }
}

// ---------------- decode: out[32768,256] = outs_bf @ W_dec^T + b_dec ----------------
__global__ __launch_bounds__(256) void decode_kernel(
    const unsigned short* __restrict__ A,    // outs bf16 [32768][1024]
    const unsigned short* __restrict__ Wd,   // W_dec bf16 [256][1024]
    const float* __restrict__ bdec,
    float* __restrict__ out)                 // [32768][256]
{
  __shared__ __align__(16) unsigned char Asm[64 * 128];
  const int tid = threadIdx.x;
  const int w = tid >> 6;
  const int lane = tid & 63;
  const int ln = lane & 15, kg = lane >> 4;
  const int m0 = blockIdx.x * 64;
  const int nb = w * 64;                     // 4 waves cover N=256
  const int srow = tid >> 2, skq = tid & 3;

  f32x4 acc[4][4];
  for (int a = 0; a < 4; ++a) for (int b = 0; b < 4; ++b) acc[a][b] = (f32x4){0.f,0.f,0.f,0.f};

  for (int kc = 0; kc < 16; ++kc) {          // K=1024 in chunks of 64
    {
      const unsigned short* src = A + (m0 + srow) * 1024 + kc * 64 + skq * 16;
      unsigned base = (unsigned)(srow * 128 + skq * 32);
      unsigned sw = (unsigned)((srow & 7) << 4);
      *(i32x4*)(Asm + ((base) ^ sw))      = *(const i32x4*)(src);
      *(i32x4*)(Asm + ((base + 16) ^ sw)) = *(const i32x4*)(src + 8);
    }
    __syncthreads();
    for (int kk = 0; kk < 2; ++kk) {
      bf16x8 afr[4];
      for (int mi = 0; mi < 4; ++mi) {
        int row = mi * 16 + ln;
        unsigned off = (unsigned)(row * 128 + (kk * 32 + kg * 8) * 2);
        afr[mi] = *(const bf16x8*)(Asm + (off ^ ((unsigned)(row & 7) << 4)));
      }
      for (int ni = 0; ni < 4; ++ni) {
        const unsigned short* bp = Wd + (nb + ni * 16 + ln) * 1024 + kc * 64 + kk * 32 + kg * 8;
        bf16x8 bfr = *(const bf16x8*)bp;
        for (int mi = 0; mi < 4; ++mi)
          acc[mi][ni] = __builtin_amdgcn_mfma_f32_16x16x32_bf16(afr[mi], bfr, acc[mi][ni], 0, 0, 0);
      }
    }
    __syncthreads();
  }
  for (int ni = 0; ni < 4; ++ni) {
    int nn = nb + ni * 16 + ln;
    float bd = bdec[nn];
    for (int mi = 0; mi < 4; ++mi) {
      int mr = m0 + mi * 16 + kg * 4;
      for (int r = 0; r < 4; ++r)
        out[(mr + r) * 256 + nn] = acc[mi][ni][r] + bd;
    }
  }
}

// ---------------- host ----------------
extern "C" void kernel_launch(void* const* d_in, const int* in_sizes, int n_in,
                              void* d_out, int out_size, void* d_ws, size_t ws_size,
                              hipStream_t stream) {
  const int*   ints = (const int*)  d_in[0];
  const float* enc  = (const float*)d_in[1];
  const float* out0 = (const float*)d_in[2];
  const float* mem0 = (const float*)d_in[3];
  const float* Wih  = (const float*)d_in[4];
  const float* Whh  = (const float*)d_in[5];
  const float* bih  = (const float*)d_in[6];
  const float* bhh  = (const float*)d_in[7];
  const float* Wdec = (const float*)d_in[8];
  const float* bdec = (const float*)d_in[9];
  float* out = (float*)d_out;

  char* ws = (char*)d_ws;
  size_t off = 0;
  auto alloc = [&](size_t bytes) { char* p = ws + off; off += (bytes + 255) & ~(size_t)255; return p; };
  unsigned short* Whh_bf  = (unsigned short*)alloc(4096ull * 1024 * 2);     // 8 MB
  unsigned short* enc_bf  = (unsigned short*)alloc(256ull * 512 * 2);
  unsigned short* Wih_bf  = (unsigned short*)alloc(4096ull * 512 * 2);      // 4 MB
  unsigned short* Wdec_bf = (unsigned short*)alloc(256ull * 1024 * 2);
  float*          proj    = (float*)alloc(256ull * 4096 * 4);               // 4 MB packed
  unsigned short* outs_bf = (unsigned short*)alloc(512ull * 64 * 1024 * 2); // 64 MB
  unsigned int*   hcomm   = (unsigned int*)alloc(2ull * 64 * 1024 * 4);     // 512 KB
  // total ~81 MB of ws

  // Zero the tag ring every launch (first call sees recycled ws garbage;
  // tag 0 never matches any target).
  hipMemsetAsync(hcomm, 0, 2ull * 64 * 1024 * 4, stream);

  cvt_bf16<<<512, 256, 0, stream>>>(Whh,  Whh_bf,  4096 * 1024 / 4);
  cvt_bf16<<<64,  256, 0, stream>>>(enc,  enc_bf,  256 * 512 / 4);
  cvt_bf16<<<256, 256, 0, stream>>>(Wih,  Wih_bf,  4096 * 512 / 4);
  cvt_bf16<<<64,  256, 0, stream>>>(Wdec, Wdec_bf, 256 * 1024 / 4);

  proj_kernel<<<dim3(4, 16), 256, 0, stream>>>(enc_bf, Wih_bf, bih, bhh, proj);

  {
    const unsigned short* a0 = Whh_bf;
    const float* a1 = proj;
    const int* a2 = ints;
    const float* a3 = out0;
    const float* a4 = mem0;
    unsigned int* a5 = hcomm;
    unsigned short* a6 = outs_bf;
    void* args[] = { &a0, &a1, &a2, &a3, &a4, &a5, &a6 };
    hipError_t e = hipLaunchCooperativeKernel((const void*)scan_kernel,
                                              dim3(256), dim3(256), args, 0, stream);
    if (e != hipSuccess) {
      // fallback: plain launch; 256 blocks co-resident (16 KB LDS, 1 blk/CU)
      scan_kernel<<<256, 256, 0, stream>>>(Whh_bf, proj, ints, out0, mem0,
                                           hcomm, outs_bf);
    }
  }

  decode_kernel<<<512, 256, 0, stream>>>(outs_bf, Wdec_bf, bdec, out);
}

// Round 6
// 2346.937 us; speedup vs baseline: 1.0155x; 1.0155x over previous
//
#include <hip/hip_runtime.h>

// LSTMCharacterPredictor — round 6: R4 protocol + sleep-throttled poll.
// T=512 B=64 E=512 H=1024 V=256.
// R5 post-mortem: sentinel+atomic-swap regressed (confounded pair); reverted.
// R2/R4/R5 all plateau at 4.1-4.6us/step though chain arithmetic says ~1.5us
// -> hypothesis: continuous sc1 poll traffic (290 GB/s at MALL) queues the
// publish/detect flights themselves. Single-variable test: R4 + s_sleep(4)
// backoff on failed poll rounds (3x less MALL pressure, +<=0.12us detect
// quantization). Publish = plain sc0sc1 store (R4). Packed proj kept (R5).

#define TT 512
#define BB 64
#define HH 1024
#define VV 256
#define EE 512

typedef __attribute__((ext_vector_type(8))) short bf16x8;
typedef __attribute__((ext_vector_type(4))) float f32x4;
typedef __attribute__((ext_vector_type(4))) int i32x4;
typedef __attribute__((ext_vector_type(4))) unsigned short u16x4;

static __device__ __forceinline__ unsigned short f2bf(float f) {
  union { float f; unsigned u; } x; x.f = f;
  unsigned r = x.u + 0x7fffu + ((x.u >> 16) & 1u);   // RNE
  return (unsigned short)(r >> 16);
}

// ---------------- f32 -> bf16 convert (vectorized) ----------------
__global__ void cvt_bf16(const float* __restrict__ s, unsigned short* __restrict__ d, int n4) {
  int i = blockIdx.x * blockDim.x + threadIdx.x;
  int st = gridDim.x * blockDim.x;
  for (; i < n4; i += st) {
    f32x4 v = *(const f32x4*)(s + 4l * i);
    u16x4 o;
    o.x = f2bf(v.x); o.y = f2bf(v.y); o.z = f2bf(v.z); o.w = f2bf(v.w);
    *(u16x4*)(d + 4l * i) = o;
  }
}

// ------- proj packed: proj[v][j][u][gate] = enc@W_ih^T + b_ih + b_hh -------
__global__ __launch_bounds__(256) void proj_kernel(
    const unsigned short* __restrict__ A,    // enc bf16 [256][512]
    const unsigned short* __restrict__ Wi,   // W_ih bf16 [4096][512]
    const float* __restrict__ bih, const float* __restrict__ bhh,
    float* __restrict__ proj)                // [256][64][16][4] f32
{
  __shared__ __align__(16) unsigned char Asm[64 * 128];   // [64 m][64 k] bf16, swizzled
  const int tid = threadIdx.x;
  const int w = tid >> 6;
  const int lane = tid & 63;
  const int ln = lane & 15, kg = lane >> 4;
  const int m0 = blockIdx.x * 64;            // 4 blocks
  const int nb = blockIdx.y * 256 + w * 64;  // 16 blocks.y, wave owns 64 n
  const int srow = tid >> 2, skq = tid & 3;

  f32x4 acc[4][4];
  for (int a = 0; a < 4; ++a) for (int b = 0; b < 4; ++b) acc[a][b] = (f32x4){0.f,0.f,0.f,0.f};

  for (int kc = 0; kc < 8; ++kc) {           // K=512 in chunks of 64
    {
      const unsigned short* src = A + (m0 + srow) * 512 + kc * 64 + skq * 16;
      unsigned base = (unsigned)(srow * 128 + skq * 32);
      unsigned sw = (unsigned)((srow & 7) << 4);
      *(i32x4*)(Asm + ((base) ^ sw))      = *(const i32x4*)(src);
      *(i32x4*)(Asm + ((base + 16) ^ sw)) = *(const i32x4*)(src + 8);
    }
    __syncthreads();
    for (int kk = 0; kk < 2; ++kk) {
      bf16x8 afr[4];
      for (int mi = 0; mi < 4; ++mi) {
        int row = mi * 16 + ln;
        unsigned off = (unsigned)(row * 128 + (kk * 32 + kg * 8) * 2);
        afr[mi] = *(const bf16x8*)(Asm + (off ^ ((unsigned)(row & 7) << 4)));
      }
      for (int ni = 0; ni < 4; ++ni) {
        const unsigned short* bp = Wi + (nb + ni * 16 + ln) * 512 + kc * 64 + kk * 32 + kg * 8;
        bf16x8 bfr = *(const bf16x8*)bp;
        for (int mi = 0; mi < 4; ++mi)
          acc[mi][ni] = __builtin_amdgcn_mfma_f32_16x16x32_bf16(afr[mi], bfr, acc[mi][ni], 0, 0, 0);
      }
    }
    __syncthreads();
  }
  for (int ni = 0; ni < 4; ++ni) {
    int nn = nb + ni * 16 + ln;             // global gate-row = gi*1024 + unit
    int gi = nn >> 10, uu = nn & 1023;
    float bias = bih[nn] + bhh[nn];
    for (int mi = 0; mi < 4; ++mi) {
      int mr = m0 + mi * 16 + kg * 4;
      for (int r = 0; r < 4; ++r)
        proj[(size_t)(mr + r) * 4096 + (uu >> 4) * 64 + (uu & 15) * 4 + gi]
            = acc[mi][ni][r] + bias;
    }
  }
}

// ---------------- persistent LSTM scan (tagged-h, throttled poll) ----------------
// 256 blocks x 256 thr. group g=blk>>6 owns batches [g*16,+16); block j=blk&63
// owns hidden units [j*16,+16). Wave w holds W_hh B-frags for 4 gates over
// K-slice [w*256,+256) in VGPRs. hcomm[slot][b][u] = (bf16 h)<<16 | version,
// slot = version&1. Consumer full-load-polls its own A-words (exact tags);
// failed rounds back off with s_sleep to decongest MALL.
#define SPIN_CAP 8192

__global__ __launch_bounds__(256, 1) void scan_kernel(
    const unsigned short* __restrict__ Whh,   // bf16 [4096][1024]
    const float* __restrict__ proj,           // [256][64][16][4] f32 packed
    const int* __restrict__ ints,             // [512][64]
    const float* __restrict__ h0v,            // output0 [1024]
    const float* __restrict__ c0v,            // memory0 [1024]
    unsigned int* __restrict__ hcomm,         // [2][64][1024] tagged u32
    unsigned short* __restrict__ outs)        // bf16 [512][64][1024] h history
{
  __shared__ float gatesm[4][4][16][16];      // [w][gi][b][u] f32 partials (16 KB)

  const int tid = threadIdx.x;
  const int blk = blockIdx.x;
  const int g = blk >> 6, j = blk & 63;
  const int w = tid >> 6, lane = tid & 63;
  const int ln = lane & 15, kg = lane >> 4;
  const int b = tid >> 4, u = tid & 15;
  const int uglob = j * 16 + u;
  const int bglob = g * 16 + b;

  // W_hh B-fragments in registers: gate gi row (gi*1024 + j*16 + ln),
  // k = w*256 + kt*32 + kg*8 .. +8  (same k order as A-frags -> consistent).
  bf16x8 bw[4][8];
#pragma unroll
  for (int gi = 0; gi < 4; ++gi)
#pragma unroll
    for (int kt = 0; kt < 8; ++kt)
      bw[gi][kt] = *(const bf16x8*)(Whh + (size_t)(gi * 1024 + j * 16 + ln) * 1024
                                        + w * 256 + kt * 32 + kg * 8);

  float c = c0v[uglob];

  // publish version 1 (= h0) into slot 1; plain bf16 copy into outs[0]
  {
    float hv0 = h0v[uglob];
    unsigned short hb = f2bf(hv0);
    unsigned word = ((unsigned)hb << 16) | 1u;
    unsigned* hp = hcomm + 65536 + (size_t)bglob * 1024 + uglob;   // slot 1
    asm volatile("global_store_dword %0, %1, off sc0 sc1" :: "v"(hp), "v"(word) : "memory");
    outs[(size_t)bglob * 1024 + uglob] = hb;
  }

  for (int t = 0; t < TT - 1; ++t) {
    // ---- prefetch packed proj row (1 dwordx4/thread; drains with poll wait) ----
    int vocab = ints[t * 64 + bglob];
    f32x4 prv;
    {
      const float* pp = proj + (size_t)vocab * 4096 + j * 64 + u * 4;
      asm volatile("global_load_dwordx4 %0, %1, off" : "=v"(prv) : "v"(pp) : "memory");
    }

    // ---- poll A-words (tagged) until all 64 tags == t+1; sleep on fail ----
    // lane reads batch row (g*16+ln), k = w*256 + kg*8 + kt*32 + [0,8)
    const unsigned* ab = hcomm + ((size_t)((t + 1) & 1)) * 65536
                       + (size_t)(g * 16 + ln) * 1024 + w * 256 + kg * 8;
    unsigned tgt = (unsigned)(t + 1);
    i32x4 q[16];
    {
      int guard = 0;
      while (true) {
#define LQ(i, off_lit) \
        asm volatile("global_load_dwordx4 %0, %1, off offset:" off_lit " sc0 sc1" \
                     : "=v"(q[i]) : "v"(ab) : "memory")
        LQ(0, "0");    LQ(1, "16");   LQ(2, "128");  LQ(3, "144");
        LQ(4, "256");  LQ(5, "272");  LQ(6, "384");  LQ(7, "400");
        LQ(8, "512");  LQ(9, "528");  LQ(10, "640"); LQ(11, "656");
        LQ(12, "768"); LQ(13, "784"); LQ(14, "896"); LQ(15, "912");
#undef LQ
        asm volatile("s_waitcnt vmcnt(0)" ::: "memory");
        __builtin_amdgcn_sched_barrier(0);    // rule 18: keep checks after wait
        unsigned bad = 0;
#pragma unroll
        for (int i = 0; i < 16; ++i) {
          bad |= ((unsigned)q[i].x ^ tgt);
          bad |= ((unsigned)q[i].y ^ tgt);
          bad |= ((unsigned)q[i].z ^ tgt);
          bad |= ((unsigned)q[i].w ^ tgt);
        }
        if (__all((bad & 0xffffu) == 0u)) break;
        if (++guard > SPIN_CAP) break;        // deadlock escape (never legit)
        asm volatile("s_sleep 4" ::: "memory");  // ~256cy backoff: decongest MALL
      }
    }
    __builtin_amdgcn_sched_barrier(0);

    // ---- strip tags, pack bf16x8 A-frags ----
    bf16x8 av[8];
#pragma unroll
    for (int kt = 0; kt < 8; ++kt) {
      i32x4 lo = q[2 * kt], hi = q[2 * kt + 1];
      unsigned d0 = ((unsigned)lo.x >> 16) | ((unsigned)lo.y & 0xffff0000u);
      unsigned d1 = ((unsigned)lo.z >> 16) | ((unsigned)lo.w & 0xffff0000u);
      unsigned d2 = ((unsigned)hi.x >> 16) | ((unsigned)hi.y & 0xffff0000u);
      unsigned d3 = ((unsigned)hi.z >> 16) | ((unsigned)hi.w & 0xffff0000u);
      union { i32x4 i; bf16x8 h; } u2;
      u2.i = (i32x4){ (int)d0, (int)d1, (int)d2, (int)d3 };
      av[kt] = u2.h;
    }

    // ---- 32 MFMAs, 4 independent chains (one per gate) ----
    f32x4 ac0 = (f32x4){0.f,0.f,0.f,0.f}, ac1 = ac0, ac2 = ac0, ac3 = ac0;
#pragma unroll
    for (int kt = 0; kt < 8; ++kt) {
      ac0 = __builtin_amdgcn_mfma_f32_16x16x32_bf16(av[kt], bw[0][kt], ac0, 0, 0, 0);
      ac1 = __builtin_amdgcn_mfma_f32_16x16x32_bf16(av[kt], bw[1][kt], ac1, 0, 0, 0);
      ac2 = __builtin_amdgcn_mfma_f32_16x16x32_bf16(av[kt], bw[2][kt], ac2, 0, 0, 0);
      ac3 = __builtin_amdgcn_mfma_f32_16x16x32_bf16(av[kt], bw[3][kt], ac3, 0, 0, 0);
    }

    // ---- cross-wave K-reduction via LDS ----
    // D layout: n(unit)=lane&15, m(batch)=(lane>>4)*4+r  [m89-verified]
#pragma unroll
    for (int r = 0; r < 4; ++r) {
      gatesm[w][0][kg * 4 + r][ln] = ac0[r];
      gatesm[w][1][kg * 4 + r][ln] = ac1[r];
      gatesm[w][2][kg * 4 + r][ln] = ac2[r];
      gatesm[w][3][kg * 4 + r][ln] = ac3[r];
    }
    __syncthreads();

    // ---- elementwise cell update: thread (b,u) ----
    float gi_ = prv.x, gf_ = prv.y, gg_ = prv.z, go_ = prv.w;
#pragma unroll
    for (int ww = 0; ww < 4; ++ww) {
      gi_ += gatesm[ww][0][b][u];
      gf_ += gatesm[ww][1][b][u];
      gg_ += gatesm[ww][2][b][u];
      go_ += gatesm[ww][3][b][u];
    }
    float ii = __builtin_amdgcn_rcpf(1.f + __expf(-gi_));
    float ff = __builtin_amdgcn_rcpf(1.f + __expf(-gf_));
    float gt = 1.f - 2.f * __builtin_amdgcn_rcpf(1.f + __expf(2.f * gg_));
    float oo = __builtin_amdgcn_rcpf(1.f + __expf(-go_));
    c = ff * c + ii * gt;
    float hv = oo * (1.f - 2.f * __builtin_amdgcn_rcpf(1.f + __expf(2.f * c)));

    // ---- publish version t+2 (plain sc0sc1 store) + outs[t+1] ----
    {
      unsigned short hb = f2bf(hv);
      unsigned word = ((unsigned)hb << 16) | ((unsigned)(t + 2) & 0xffffu);
      unsigned* hp = hcomm + ((size_t)((t + 2) & 1)) * 65536
                   + (size_t)bglob * 1024 + uglob;
      asm volatile("global_store_dword %0, %1, off sc0 sc1" :: "v"(hp), "v"(word) : "memory");
      outs[(size_t)(t + 1) * 65536 + (size_t)bglob * 1024 + uglob] = hb;
    }
    // WAR guard for gatesm across steps.
    __syncthreads();
  }
}

// ---------------- decode: out[32768,256] = outs_bf @ W_dec^T + b_dec ----------------
__global__ __launch_bounds__(256) void decode_kernel(
    const unsigned short* __restrict__ A,    // outs bf16 [32768][1024]
    const unsigned short* __restrict__ Wd,   // W_dec bf16 [256][1024]
    const float* __restrict__ bdec,
    float* __restrict__ out)                 // [32768][256]
{
  __shared__ __align__(16) unsigned char Asm[64 * 128];
  const int tid = threadIdx.x;
  const int w = tid >> 6;
  const int lane = tid & 63;
  const int ln = lane & 15, kg = lane >> 4;
  const int m0 = blockIdx.x * 64;
  const int nb = w * 64;                     // 4 waves cover N=256
  const int srow = tid >> 2, skq = tid & 3;

  f32x4 acc[4][4];
  for (int a = 0; a < 4; ++a) for (int b = 0; b < 4; ++b) acc[a][b] = (f32x4){0.f,0.f,0.f,0.f};

  for (int kc = 0; kc < 16; ++kc) {          // K=1024 in chunks of 64
    {
      const unsigned short* src = A + (m0 + srow) * 1024 + kc * 64 + skq * 16;
      unsigned base = (unsigned)(srow * 128 + skq * 32);
      unsigned sw = (unsigned)((srow & 7) << 4);
      *(i32x4*)(Asm + ((base) ^ sw))      = *(const i32x4*)(src);
      *(i32x4*)(Asm + ((base + 16) ^ sw)) = *(const i32x4*)(src + 8);
    }
    __syncthreads();
    for (int kk = 0; kk < 2; ++kk) {
      bf16x8 afr[4];
      for (int mi = 0; mi < 4; ++mi) {
        int row = mi * 16 + ln;
        unsigned off = (unsigned)(row * 128 + (kk * 32 + kg * 8) * 2);
        afr[mi] = *(const bf16x8*)(Asm + (off ^ ((unsigned)(row & 7) << 4)));
      }
      for (int ni = 0; ni < 4; ++ni) {
        const unsigned short* bp = Wd + (nb + ni * 16 + ln) * 1024 + kc * 64 + kk * 32 + kg * 8;
        bf16x8 bfr = *(const bf16x8*)bp;
        for (int mi = 0; mi < 4; ++mi)
          acc[mi][ni] = __builtin_amdgcn_mfma_f32_16x16x32_bf16(afr[mi], bfr, acc[mi][ni], 0, 0, 0);
      }
    }
    __syncthreads();
  }
  for (int ni = 0; ni < 4; ++ni) {
    int nn = nb + ni * 16 + ln;
    float bd = bdec[nn];
    for (int mi = 0; mi < 4; ++mi) {
      int mr = m0 + mi * 16 + kg * 4;
      for (int r = 0; r < 4; ++r)
        out[(mr + r) * 256 + nn] = acc[mi][ni][r] + bd;
    }
  }
}

// ---------------- host ----------------
extern "C" void kernel_launch(void* const* d_in, const int* in_sizes, int n_in,
                              void* d_out, int out_size, void* d_ws, size_t ws_size,
                              hipStream_t stream) {
  const int*   ints = (const int*)  d_in[0];
  const float* enc  = (const float*)d_in[1];
  const float* out0 = (const float*)d_in[2];
  const float* mem0 = (const float*)d_in[3];
  const float* Wih  = (const float*)d_in[4];
  const float* Whh  = (const float*)d_in[5];
  const float* bih  = (const float*)d_in[6];
  const float* bhh  = (const float*)d_in[7];
  const float* Wdec = (const float*)d_in[8];
  const float* bdec = (const float*)d_in[9];
  float* out = (float*)d_out;

  char* ws = (char*)d_ws;
  size_t off = 0;
  auto alloc = [&](size_t bytes) { char* p = ws + off; off += (bytes + 255) & ~(size_t)255; return p; };
  unsigned short* Whh_bf  = (unsigned short*)alloc(4096ull * 1024 * 2);     // 8 MB
  unsigned short* enc_bf  = (unsigned short*)alloc(256ull * 512 * 2);
  unsigned short* Wih_bf  = (unsigned short*)alloc(4096ull * 512 * 2);      // 4 MB
  unsigned short* Wdec_bf = (unsigned short*)alloc(256ull * 1024 * 2);
  float*          proj    = (float*)alloc(256ull * 4096 * 4);               // 4 MB packed
  unsigned short* outs_bf = (unsigned short*)alloc(512ull * 64 * 1024 * 2); // 64 MB
  unsigned int*   hcomm   = (unsigned int*)alloc(2ull * 64 * 1024 * 4);     // 512 KB
  // total ~81 MB of ws

  // Zero the tag ring every launch (first call sees recycled ws garbage;
  // tag 0 never matches any target).
  hipMemsetAsync(hcomm, 0, 2ull * 64 * 1024 * 4, stream);

  cvt_bf16<<<512, 256, 0, stream>>>(Whh,  Whh_bf,  4096 * 1024 / 4);
  cvt_bf16<<<64,  256, 0, stream>>>(enc,  enc_bf,  256 * 512 / 4);
  cvt_bf16<<<256, 256, 0, stream>>>(Wih,  Wih_bf,  4096 * 512 / 4);
  cvt_bf16<<<64,  256, 0, stream>>>(Wdec, Wdec_bf, 256 * 1024 / 4);

  proj_kernel<<<dim3(4, 16), 256, 0, stream>>>(enc_bf, Wih_bf, bih, bhh, proj);

  {
    const unsigned short* a0 = Whh_bf;
    const float* a1 = proj;
    const int* a2 = ints;
    const float* a3 = out0;
    const float* a4 = mem0;
    unsigned int* a5 = hcomm;
    unsigned short* a6 = outs_bf;
    void* args[] = { &a0, &a1, &a2, &a3, &a4, &a5, &a6 };
    hipError_t e = hipLaunchCooperativeKernel((const void*)scan_kernel,
                                              dim3(256), dim3(256), args, 0, stream);
    if (e != hipSuccess) {
      // fallback: plain launch; 256 blocks co-resident (16 KB LDS, 1 blk/CU)
      scan_kernel<<<256, 256, 0, stream>>>(Whh_bf, proj, ints, out0, mem0,
                                           hcomm, outs_bf);
    }
  }

  decode_kernel<<<512, 256, 0, stream>>>(outs_bf, Wdec_bf, bdec, out);
}

// Round 8
// 1906.993 us; speedup vs baseline: 1.2498x; 1.2307x over previous
//
#include <hip/hip_runtime.h>

// LSTMCharacterPredictor — round 8: small-group scan (8 groups x 32 blocks),
// GLOBAL sc0sc1 protocol only. T=512 B=64 E=512 H=1024 V=256.
// R7 post-mortem: XCD self-org's LOCAL (sc0-only) mode deadlocked -> XCC_ID
// co-location can't be trusted to carry correctness. R8 keeps R7's fan-in
// restructure (8 samples/group, 32 producers, 32 units/block, W in VGPRs)
// with the proven sc1 tagged protocol and a STATIC mapping g=blk&7 (XCD-affine
// under round-robin dispatch as a heuristic only). Single-variable vs R4:
// group size 64->32 blocks / 16->8 samples; poll traffic halved.

#define TT 512
#define BB 64
#define HH 1024
#define VV 256
#define EE 512
#define SPIN_CAP 16384

typedef __attribute__((ext_vector_type(8))) short bf16x8;
typedef __attribute__((ext_vector_type(4))) float f32x4;
typedef __attribute__((ext_vector_type(4))) int i32x4;
typedef __attribute__((ext_vector_type(4))) unsigned short u16x4;

static __device__ __forceinline__ unsigned short f2bf(float f) {
  union { float f; unsigned u; } x; x.f = f;
  unsigned r = x.u + 0x7fffu + ((x.u >> 16) & 1u);   // RNE
  return (unsigned short)(r >> 16);
}

// ---------------- f32 -> bf16 convert (vectorized) ----------------
__global__ void cvt_bf16(const float* __restrict__ s, unsigned short* __restrict__ d, int n4) {
  int i = blockIdx.x * blockDim.x + threadIdx.x;
  int st = gridDim.x * blockDim.x;
  for (; i < n4; i += st) {
    f32x4 v = *(const f32x4*)(s + 4l * i);
    u16x4 o;
    o.x = f2bf(v.x); o.y = f2bf(v.y); o.z = f2bf(v.z); o.w = f2bf(v.w);
    *(u16x4*)(d + 4l * i) = o;
  }
}

// ------- proj packed: proj[v][unit][gate] = enc@W_ih^T + b_ih + b_hh -------
__global__ __launch_bounds__(256) void proj_kernel(
    const unsigned short* __restrict__ A,    // enc bf16 [256][512]
    const unsigned short* __restrict__ Wi,   // W_ih bf16 [4096][512]
    const float* __restrict__ bih, const float* __restrict__ bhh,
    float* __restrict__ proj)                // [256][1024][4] f32
{
  __shared__ __align__(16) unsigned char Asm[64 * 128];   // [64 m][64 k] bf16, swizzled
  const int tid = threadIdx.x;
  const int w = tid >> 6;
  const int lane = tid & 63;
  const int ln = lane & 15, kg = lane >> 4;
  const int m0 = blockIdx.x * 64;            // 4 blocks
  const int nb = blockIdx.y * 256 + w * 64;  // 16 blocks.y, wave owns 64 n
  const int srow = tid >> 2, skq = tid & 3;

  f32x4 acc[4][4];
  for (int a = 0; a < 4; ++a) for (int b = 0; b < 4; ++b) acc[a][b] = (f32x4){0.f,0.f,0.f,0.f};

  for (int kc = 0; kc < 8; ++kc) {           // K=512 in chunks of 64
    {
      const unsigned short* src = A + (m0 + srow) * 512 + kc * 64 + skq * 16;
      unsigned base = (unsigned)(srow * 128 + skq * 32);
      unsigned sw = (unsigned)((srow & 7) << 4);
      *(i32x4*)(Asm + ((base) ^ sw))      = *(const i32x4*)(src);
      *(i32x4*)(Asm + ((base + 16) ^ sw)) = *(const i32x4*)(src + 8);
    }
    __syncthreads();
    for (int kk = 0; kk < 2; ++kk) {
      bf16x8 afr[4];
      for (int mi = 0; mi < 4; ++mi) {
        int row = mi * 16 + ln;
        unsigned off = (unsigned)(row * 128 + (kk * 32 + kg * 8) * 2);
        afr[mi] = *(const bf16x8*)(Asm + (off ^ ((unsigned)(row & 7) << 4)));
      }
      for (int ni = 0; ni < 4; ++ni) {
        const unsigned short* bp = Wi + (nb + ni * 16 + ln) * 512 + kc * 64 + kk * 32 + kg * 8;
        bf16x8 bfr = *(const bf16x8*)bp;
        for (int mi = 0; mi < 4; ++mi)
          acc[mi][ni] = __builtin_amdgcn_mfma_f32_16x16x32_bf16(afr[mi], bfr, acc[mi][ni], 0, 0, 0);
      }
    }
    __syncthreads();
  }
  for (int ni = 0; ni < 4; ++ni) {
    int nn = nb + ni * 16 + ln;             // global gate-row = gi*1024 + unit
    int gi = nn >> 10, uu = nn & 1023;
    float bias = bih[nn] + bhh[nn];
    for (int mi = 0; mi < 4; ++mi) {
      int mr = m0 + mi * 16 + kg * 4;
      for (int r = 0; r < 4; ++r)
        proj[(size_t)(mr + r) * 4096 + uu * 4 + gi] = acc[mi][ni][r] + bias;
    }
  }
}

// ---------------- persistent LSTM scan (small groups, tagged-h) ----------------
// group g=blk&7 owns samples [g*8,+8); slice r=blk>>3 owns units [r*32,+32).
// Wave w: K-slice [w*256,+256) of the 128 local gate rows (4 gates x 32 units);
// W B-frags bw[8 n-tiles][8 k-tiles] in VGPRs. MFMA M=16: rows 0..7 real
// samples, rows 8..15 zero pads (D-row independence -> no contamination).
// hcomm[slot][sample][unit] = (bf16 h)<<16 | version, slot=version&1.
// Ring-depth-2 safety: producer publishes t+2 only after polling ALL of its
// group's version t+1, which implies every sibling finished reading version t.
__global__ __launch_bounds__(256, 1) void scan_kernel(
    const unsigned short* __restrict__ Whh,   // bf16 [4096][1024]
    const float* __restrict__ proj,           // [256][1024][4] f32 packed
    const int* __restrict__ ints,             // [512][64]
    const float* __restrict__ h0v,            // output0 [1024]
    const float* __restrict__ c0v,            // memory0 [1024]
    unsigned int* __restrict__ hcomm,         // [2][64][1024] tagged u32
    unsigned short* __restrict__ outs)        // bf16 [512][64][1024] h history
{
  __shared__ float gatesm[4 * 8 * 128];       // [w][sample(8)][localrow(128)] 16 KB

  const int tid = threadIdx.x;
  const int blk = blockIdx.x;
  const int g = blk & 7, r = blk >> 3;        // XCD-affine heuristic mapping
  const int w = tid >> 6, lane = tid & 63;
  const int ln = lane & 15, kg = lane >> 4;
  const int s = tid >> 5, u = tid & 31;       // elementwise cell (sample, unit)
  const int sg = g * 8 + s;
  const int ug = r * 32 + u;

  // W_hh B-frags: local gate-row lrow=nt*16+ln -> global row
  // (lrow>>5)*1024 + r*32 + (lrow&31); k = w*256 + kt*32 + kg*8 + [0,8).
  bf16x8 bw[8][8];
#pragma unroll
  for (int nt = 0; nt < 8; ++nt) {
    int lrow = nt * 16 + ln;
    int grow = (lrow >> 5) * 1024 + r * 32 + (lrow & 31);
    const unsigned short* wp = Whh + (size_t)grow * 1024 + w * 256 + kg * 8;
#pragma unroll
    for (int kt = 0; kt < 8; ++kt)
      bw[nt][kt] = *(const bf16x8*)(wp + kt * 32);
  }

  float c = c0v[ug];

  // publish version 1 (= h0) into slot 1; outs[0]
  {
    unsigned short hb = f2bf(h0v[ug]);
    unsigned word = ((unsigned)hb << 16) | 1u;
    unsigned* hp = hcomm + 65536 + (size_t)sg * 1024 + ug;
    asm volatile("global_store_dword %0, %1, off sc0 sc1" :: "v"(hp), "v"(word) : "memory");
    outs[(size_t)sg * 1024 + ug] = hb;
  }

  i32x4 q[16];
#pragma unroll
  for (int i = 0; i < 16; ++i) q[i] = (i32x4){0, 0, 0, 0};

  for (int t = 0; t < TT - 1; ++t) {
    // ---- prefetch packed proj (1 dwordx4/thread; poll's vmcnt drains it) ----
    int vocab = ints[t * 64 + sg];
    f32x4 prv;
    { const float* pp = proj + (size_t)vocab * 4096 + ug * 4;
      asm volatile("global_load_dwordx4 %0, %1, off" : "=v"(prv) : "v"(pp) : "memory"); }

    // ---- poll A-rows (lanes ln<8 = real samples; ln>=8 pads keep q=0) ----
    const unsigned* ab = hcomm + ((size_t)((t + 1) & 1)) * 65536
                       + (size_t)(g * 8 + (ln & 7)) * 1024 + w * 256 + kg * 8;
    unsigned tgt = (unsigned)(t + 1);
    {
      int guard = 0;
      while (true) {
        if (ln < 8) {
#define LQ(i, off_lit) \
          asm volatile("global_load_dwordx4 %0, %1, off offset:" off_lit " sc0 sc1" \
                       : "=v"(q[i]) : "v"(ab) : "memory")
          LQ(0, "0");    LQ(1, "16");   LQ(2, "128");  LQ(3, "144");
          LQ(4, "256");  LQ(5, "272");  LQ(6, "384");  LQ(7, "400");
          LQ(8, "512");  LQ(9, "528");  LQ(10, "640"); LQ(11, "656");
          LQ(12, "768"); LQ(13, "784"); LQ(14, "896"); LQ(15, "912");
#undef LQ
        }
        asm volatile("s_waitcnt vmcnt(0)" ::: "memory");
        __builtin_amdgcn_sched_barrier(0);    // rule 18: keep checks after wait
        unsigned bad = 0;
        if (ln < 8) {
#pragma unroll
          for (int i = 0; i < 16; ++i) {
            bad |= ((unsigned)q[i].x ^ tgt);
            bad |= ((unsigned)q[i].y ^ tgt);
            bad |= ((unsigned)q[i].z ^ tgt);
            bad |= ((unsigned)q[i].w ^ tgt);
          }
        }
        if (__all(ln >= 8 || (bad & 0xffffu) == 0u)) break;
        if (++guard > SPIN_CAP) break;        // deadlock escape (never legit)
      }
    }
    __builtin_amdgcn_sched_barrier(0);

    // ---- unpack + 64 MFMAs (8 independent n-tile chains) ----
    f32x4 acc[8];
#pragma unroll
    for (int i = 0; i < 8; ++i) acc[i] = (f32x4){0.f,0.f,0.f,0.f};
#pragma unroll
    for (int kt = 0; kt < 8; ++kt) {
      i32x4 lo = q[2 * kt], hi = q[2 * kt + 1];
      unsigned d0 = ((unsigned)lo.x >> 16) | ((unsigned)lo.y & 0xffff0000u);
      unsigned d1 = ((unsigned)lo.z >> 16) | ((unsigned)lo.w & 0xffff0000u);
      unsigned d2 = ((unsigned)hi.x >> 16) | ((unsigned)hi.y & 0xffff0000u);
      unsigned d3 = ((unsigned)hi.z >> 16) | ((unsigned)hi.w & 0xffff0000u);
      union { i32x4 i; bf16x8 h; } u2;
      u2.i = (i32x4){ (int)d0, (int)d1, (int)d2, (int)d3 };
#pragma unroll
      for (int nt = 0; nt < 8; ++nt)
        acc[nt] = __builtin_amdgcn_mfma_f32_16x16x32_bf16(u2.h, bw[nt][kt], acc[nt], 0, 0, 0);
    }

    // ---- partials to LDS: m=kg*4+rr (sample, keep m<8), n=nt*16+ln ----
#pragma unroll
    for (int nt = 0; nt < 8; ++nt) {
      if (kg < 2) {
#pragma unroll
        for (int rr = 0; rr < 4; ++rr)
          gatesm[(w * 8 + kg * 4 + rr) * 128 + nt * 16 + ln] = acc[nt][rr];
      }
    }
    __syncthreads();

    // ---- elementwise cell update: thread (s,u) ----
    float g0 = prv.x, g1 = prv.y, g2 = prv.z, g3 = prv.w;
#pragma unroll
    for (int ww = 0; ww < 4; ++ww) {
      const float* gm = gatesm + (ww * 8 + s) * 128 + u;
      g0 += gm[0];     // gate i: localrow u
      g1 += gm[32];    // gate f: localrow 32+u
      g2 += gm[64];    // gate g
      g3 += gm[96];    // gate o
    }
    float ii = __builtin_amdgcn_rcpf(1.f + __expf(-g0));
    float ff = __builtin_amdgcn_rcpf(1.f + __expf(-g1));
    float gt = 1.f - 2.f * __builtin_amdgcn_rcpf(1.f + __expf(2.f * g2));
    float oo = __builtin_amdgcn_rcpf(1.f + __expf(-g3));
    c = ff * c + ii * gt;
    float hv = oo * (1.f - 2.f * __builtin_amdgcn_rcpf(1.f + __expf(2.f * c)));

    // ---- publish version t+2 + outs[t+1] ----
    {
      unsigned short hb = f2bf(hv);
      unsigned word = ((unsigned)hb << 16) | ((unsigned)(t + 2) & 0xffffu);
      unsigned* hp = hcomm + ((size_t)((t + 2) & 1)) * 65536 + (size_t)sg * 1024 + ug;
      asm volatile("global_store_dword %0, %1, off sc0 sc1" :: "v"(hp), "v"(word) : "memory");
      outs[(size_t)(t + 1) * 65536 + (size_t)sg * 1024 + ug] = hb;
    }
    __syncthreads();   // WAR guard for gatesm across steps
  }
}

// ---------------- decode: out[32768,256] = outs_bf @ W_dec^T + b_dec ----------------
__global__ __launch_bounds__(256) void decode_kernel(
    const unsigned short* __restrict__ A,    // outs bf16 [32768][1024]
    const unsigned short* __restrict__ Wd,   // W_dec bf16 [256][1024]
    const float* __restrict__ bdec,
    float* __restrict__ out)                 // [32768][256]
{
  __shared__ __align__(16) unsigned char Asm[64 * 128];
  const int tid = threadIdx.x;
  const int w = tid >> 6;
  const int lane = tid & 63;
  const int ln = lane & 15, kg = lane >> 4;
  const int m0 = blockIdx.x * 64;
  const int nb = w * 64;                     // 4 waves cover N=256
  const int srow = tid >> 2, skq = tid & 3;

  f32x4 acc[4][4];
  for (int a = 0; a < 4; ++a) for (int b = 0; b < 4; ++b) acc[a][b] = (f32x4){0.f,0.f,0.f,0.f};

  for (int kc = 0; kc < 16; ++kc) {          // K=1024 in chunks of 64
    {
      const unsigned short* src = A + (m0 + srow) * 1024 + kc * 64 + skq * 16;
      unsigned base = (unsigned)(srow * 128 + skq * 32);
      unsigned sw = (unsigned)((srow & 7) << 4);
      *(i32x4*)(Asm + ((base) ^ sw))      = *(const i32x4*)(src);
      *(i32x4*)(Asm + ((base + 16) ^ sw)) = *(const i32x4*)(src + 8);
    }
    __syncthreads();
    for (int kk = 0; kk < 2; ++kk) {
      bf16x8 afr[4];
      for (int mi = 0; mi < 4; ++mi) {
        int row = mi * 16 + ln;
        unsigned off = (unsigned)(row * 128 + (kk * 32 + kg * 8) * 2);
        afr[mi] = *(const bf16x8*)(Asm + (off ^ ((unsigned)(row & 7) << 4)));
      }
      for (int ni = 0; ni < 4; ++ni) {
        const unsigned short* bp = Wd + (nb + ni * 16 + ln) * 1024 + kc * 64 + kk * 32 + kg * 8;
        bf16x8 bfr = *(const bf16x8*)bp;
        for (int mi = 0; mi < 4; ++mi)
          acc[mi][ni] = __builtin_amdgcn_mfma_f32_16x16x32_bf16(afr[mi], bfr, acc[mi][ni], 0, 0, 0);
      }
    }
    __syncthreads();
  }
  for (int ni = 0; ni < 4; ++ni) {
    int nn = nb + ni * 16 + ln;
    float bd = bdec[nn];
    for (int mi = 0; mi < 4; ++mi) {
      int mr = m0 + mi * 16 + kg * 4;
      for (int r = 0; r < 4; ++r)
        out[(mr + r) * 256 + nn] = acc[mi][ni][r] + bd;
    }
  }
}

// ---------------- host ----------------
extern "C" void kernel_launch(void* const* d_in, const int* in_sizes, int n_in,
                              void* d_out, int out_size, void* d_ws, size_t ws_size,
                              hipStream_t stream) {
  const int*   ints = (const int*)  d_in[0];
  const float* enc  = (const float*)d_in[1];
  const float* out0 = (const float*)d_in[2];
  const float* mem0 = (const float*)d_in[3];
  const float* Wih  = (const float*)d_in[4];
  const float* Whh  = (const float*)d_in[5];
  const float* bih  = (const float*)d_in[6];
  const float* bhh  = (const float*)d_in[7];
  const float* Wdec = (const float*)d_in[8];
  const float* bdec = (const float*)d_in[9];
  float* out = (float*)d_out;

  char* ws = (char*)d_ws;
  size_t off = 0;
  auto alloc = [&](size_t bytes) { char* p = ws + off; off += (bytes + 255) & ~(size_t)255; return p; };
  unsigned short* Whh_bf  = (unsigned short*)alloc(4096ull * 1024 * 2);     // 8 MB
  unsigned short* enc_bf  = (unsigned short*)alloc(256ull * 512 * 2);
  unsigned short* Wih_bf  = (unsigned short*)alloc(4096ull * 512 * 2);      // 4 MB
  unsigned short* Wdec_bf = (unsigned short*)alloc(256ull * 1024 * 2);
  float*          proj    = (float*)alloc(256ull * 4096 * 4);               // 4 MB packed
  unsigned short* outs_bf = (unsigned short*)alloc(512ull * 64 * 1024 * 2); // 64 MB
  unsigned int*   hcomm   = (unsigned int*)alloc(2ull * 64 * 1024 * 4);     // 512 KB
  // total ~81 MB of ws

  // Zero the tag ring every launch (first call sees recycled ws garbage;
  // tag 0 never matches any target).
  hipMemsetAsync(hcomm, 0, 2ull * 64 * 1024 * 4, stream);

  cvt_bf16<<<512, 256, 0, stream>>>(Whh,  Whh_bf,  4096 * 1024 / 4);
  cvt_bf16<<<64,  256, 0, stream>>>(enc,  enc_bf,  256 * 512 / 4);
  cvt_bf16<<<256, 256, 0, stream>>>(Wih,  Wih_bf,  4096 * 512 / 4);
  cvt_bf16<<<64,  256, 0, stream>>>(Wdec, Wdec_bf, 256 * 1024 / 4);

  proj_kernel<<<dim3(4, 16), 256, 0, stream>>>(enc_bf, Wih_bf, bih, bhh, proj);

  {
    const unsigned short* a0 = Whh_bf;
    const float* a1 = proj;
    const int* a2 = ints;
    const float* a3 = out0;
    const float* a4 = mem0;
    unsigned int* a5 = hcomm;
    unsigned short* a6 = outs_bf;
    void* args[] = { &a0, &a1, &a2, &a3, &a4, &a5, &a6 };
    hipError_t e = hipLaunchCooperativeKernel((const void*)scan_kernel,
                                              dim3(256), dim3(256), args, 0, stream);
    if (e != hipSuccess) {
      // fallback: plain launch; ~400 VGPR -> 1 blk/CU, 256 blocks co-resident
      scan_kernel<<<256, 256, 0, stream>>>(Whh_bf, proj, ints, out0, mem0,
                                           hcomm, outs_bf);
    }
  }

  decode_kernel<<<512, 256, 0, stream>>>(outs_bf, Wdec_bf, bdec, out);
}

// Round 9
// 1844.023 us; speedup vs baseline: 1.2925x; 1.0341x over previous
//
#include <hip/hip_runtime.h>

// LSTMCharacterPredictor — round 9: R8 + W-fragment register pinning.
// T=512 B=64 E=512 H=1024 V=256.
// R8 post-mortem: VGPR_Count=196 < 256 declared W regs -> compiler was
// REMATERIALIZING the W loads inside the t-loop (re-reading 256KB/block/step
// from L2/L3, ~2us/step on the critical path). Fix: pin each bw fragment with
// asm volatile("" : "+v"(frag)) after the pre-loop load — asm outputs can't
// be rematerialized, forcing true VGPR residency (~390 peak regs < 512
// budget at launch_bounds(256,1)). Single-variable change vs R8.

#define TT 512
#define BB 64
#define HH 1024
#define VV 256
#define EE 512
#define SPIN_CAP 16384

typedef __attribute__((ext_vector_type(8))) short bf16x8;
typedef __attribute__((ext_vector_type(4))) float f32x4;
typedef __attribute__((ext_vector_type(4))) int i32x4;
typedef __attribute__((ext_vector_type(4))) unsigned short u16x4;

static __device__ __forceinline__ unsigned short f2bf(float f) {
  union { float f; unsigned u; } x; x.f = f;
  unsigned r = x.u + 0x7fffu + ((x.u >> 16) & 1u);   // RNE
  return (unsigned short)(r >> 16);
}

// ---------------- f32 -> bf16 convert (vectorized) ----------------
__global__ void cvt_bf16(const float* __restrict__ s, unsigned short* __restrict__ d, int n4) {
  int i = blockIdx.x * blockDim.x + threadIdx.x;
  int st = gridDim.x * blockDim.x;
  for (; i < n4; i += st) {
    f32x4 v = *(const f32x4*)(s + 4l * i);
    u16x4 o;
    o.x = f2bf(v.x); o.y = f2bf(v.y); o.z = f2bf(v.z); o.w = f2bf(v.w);
    *(u16x4*)(d + 4l * i) = o;
  }
}

// ------- proj packed: proj[v][unit][gate] = enc@W_ih^T + b_ih + b_hh -------
__global__ __launch_bounds__(256) void proj_kernel(
    const unsigned short* __restrict__ A,    // enc bf16 [256][512]
    const unsigned short* __restrict__ Wi,   // W_ih bf16 [4096][512]
    const float* __restrict__ bih, const float* __restrict__ bhh,
    float* __restrict__ proj)                // [256][1024][4] f32
{
  __shared__ __align__(16) unsigned char Asm[64 * 128];   // [64 m][64 k] bf16, swizzled
  const int tid = threadIdx.x;
  const int w = tid >> 6;
  const int lane = tid & 63;
  const int ln = lane & 15, kg = lane >> 4;
  const int m0 = blockIdx.x * 64;            // 4 blocks
  const int nb = blockIdx.y * 256 + w * 64;  // 16 blocks.y, wave owns 64 n
  const int srow = tid >> 2, skq = tid & 3;

  f32x4 acc[4][4];
  for (int a = 0; a < 4; ++a) for (int b = 0; b < 4; ++b) acc[a][b] = (f32x4){0.f,0.f,0.f,0.f};

  for (int kc = 0; kc < 8; ++kc) {           // K=512 in chunks of 64
    {
      const unsigned short* src = A + (m0 + srow) * 512 + kc * 64 + skq * 16;
      unsigned base = (unsigned)(srow * 128 + skq * 32);
      unsigned sw = (unsigned)((srow & 7) << 4);
      *(i32x4*)(Asm + ((base) ^ sw))      = *(const i32x4*)(src);
      *(i32x4*)(Asm + ((base + 16) ^ sw)) = *(const i32x4*)(src + 8);
    }
    __syncthreads();
    for (int kk = 0; kk < 2; ++kk) {
      bf16x8 afr[4];
      for (int mi = 0; mi < 4; ++mi) {
        int row = mi * 16 + ln;
        unsigned off = (unsigned)(row * 128 + (kk * 32 + kg * 8) * 2);
        afr[mi] = *(const bf16x8*)(Asm + (off ^ ((unsigned)(row & 7) << 4)));
      }
      for (int ni = 0; ni < 4; ++ni) {
        const unsigned short* bp = Wi + (nb + ni * 16 + ln) * 512 + kc * 64 + kk * 32 + kg * 8;
        bf16x8 bfr = *(const bf16x8*)bp;
        for (int mi = 0; mi < 4; ++mi)
          acc[mi][ni] = __builtin_amdgcn_mfma_f32_16x16x32_bf16(afr[mi], bfr, acc[mi][ni], 0, 0, 0);
      }
    }
    __syncthreads();
  }
  for (int ni = 0; ni < 4; ++ni) {
    int nn = nb + ni * 16 + ln;             // global gate-row = gi*1024 + unit
    int gi = nn >> 10, uu = nn & 1023;
    float bias = bih[nn] + bhh[nn];
    for (int mi = 0; mi < 4; ++mi) {
      int mr = m0 + mi * 16 + kg * 4;
      for (int r = 0; r < 4; ++r)
        proj[(size_t)(mr + r) * 4096 + uu * 4 + gi] = acc[mi][ni][r] + bias;
    }
  }
}

// ---------------- persistent LSTM scan (small groups, tagged-h, pinned W) ----------------
// group g=blk&7 owns samples [g*8,+8); slice r=blk>>3 owns units [r*32,+32).
// Wave w: K-slice [w*256,+256) of the 128 local gate rows (4 gates x 32 units);
// W B-frags bw[8 n-tiles][8 k-tiles] PINNED in VGPRs (asm "+v" after load).
// MFMA M=16: rows 0..7 real samples, rows 8..15 zero pads.
// hcomm[slot][sample][unit] = (bf16 h)<<16 | version, slot=version&1.
__global__ __launch_bounds__(256, 1) void scan_kernel(
    const unsigned short* __restrict__ Whh,   // bf16 [4096][1024]
    const float* __restrict__ proj,           // [256][1024][4] f32 packed
    const int* __restrict__ ints,             // [512][64]
    const float* __restrict__ h0v,            // output0 [1024]
    const float* __restrict__ c0v,            // memory0 [1024]
    unsigned int* __restrict__ hcomm,         // [2][64][1024] tagged u32
    unsigned short* __restrict__ outs)        // bf16 [512][64][1024] h history
{
  __shared__ float gatesm[4 * 8 * 128];       // [w][sample(8)][localrow(128)] 16 KB

  const int tid = threadIdx.x;
  const int blk = blockIdx.x;
  const int g = blk & 7, r = blk >> 3;        // XCD-affine heuristic mapping
  const int w = tid >> 6, lane = tid & 63;
  const int ln = lane & 15, kg = lane >> 4;
  const int s = tid >> 5, u = tid & 31;       // elementwise cell (sample, unit)
  const int sg = g * 8 + s;
  const int ug = r * 32 + u;

  // W_hh B-frags: local gate-row lrow=nt*16+ln -> global row
  // (lrow>>5)*1024 + r*32 + (lrow&31); k = w*256 + kt*32 + kg*8 + [0,8).
  bf16x8 bw[8][8];
#pragma unroll
  for (int nt = 0; nt < 8; ++nt) {
    int lrow = nt * 16 + ln;
    int grow = (lrow >> 5) * 1024 + r * 32 + (lrow & 31);
    const unsigned short* wp = Whh + (size_t)grow * 1024 + w * 256 + kg * 8;
#pragma unroll
    for (int kt = 0; kt < 8; ++kt)
      bw[nt][kt] = *(const bf16x8*)(wp + kt * 32);
  }
  // PIN: make each fragment an asm output -> not rematerializable; the
  // "memory"-clobbering protocol asm in the loop can no longer force reloads.
#pragma unroll
  for (int nt = 0; nt < 8; ++nt)
#pragma unroll
    for (int kt = 0; kt < 8; ++kt)
      asm volatile("" : "+v"(bw[nt][kt]));

  float c = c0v[ug];

  // publish version 1 (= h0) into slot 1; outs[0]
  {
    unsigned short hb = f2bf(h0v[ug]);
    unsigned word = ((unsigned)hb << 16) | 1u;
    unsigned* hp = hcomm + 65536 + (size_t)sg * 1024 + ug;
    asm volatile("global_store_dword %0, %1, off sc0 sc1" :: "v"(hp), "v"(word) : "memory");
    outs[(size_t)sg * 1024 + ug] = hb;
  }

  i32x4 q[16];
#pragma unroll
  for (int i = 0; i < 16; ++i) q[i] = (i32x4){0, 0, 0, 0};

  for (int t = 0; t < TT - 1; ++t) {
    // ---- prefetch packed proj (1 dwordx4/thread; poll's vmcnt drains it) ----
    int vocab = ints[t * 64 + sg];
    f32x4 prv;
    { const float* pp = proj + (size_t)vocab * 4096 + ug * 4;
      asm volatile("global_load_dwordx4 %0, %1, off" : "=v"(prv) : "v"(pp) : "memory"); }

    // ---- poll A-rows (lanes ln<8 = real samples; ln>=8 pads keep q=0) ----
    const unsigned* ab = hcomm + ((size_t)((t + 1) & 1)) * 65536
                       + (size_t)(g * 8 + (ln & 7)) * 1024 + w * 256 + kg * 8;
    unsigned tgt = (unsigned)(t + 1);
    {
      int guard = 0;
      while (true) {
        if (ln < 8) {
#define LQ(i, off_lit) \
          asm volatile("global_load_dwordx4 %0, %1, off offset:" off_lit " sc0 sc1" \
                       : "=v"(q[i]) : "v"(ab) : "memory")
          LQ(0, "0");    LQ(1, "16");   LQ(2, "128");  LQ(3, "144");
          LQ(4, "256");  LQ(5, "272");  LQ(6, "384");  LQ(7, "400");
          LQ(8, "512");  LQ(9, "528");  LQ(10, "640"); LQ(11, "656");
          LQ(12, "768"); LQ(13, "784"); LQ(14, "896"); LQ(15, "912");
#undef LQ
        }
        asm volatile("s_waitcnt vmcnt(0)" ::: "memory");
        __builtin_amdgcn_sched_barrier(0);    // rule 18: keep checks after wait
        unsigned bad = 0;
        if (ln < 8) {
#pragma unroll
          for (int i = 0; i < 16; ++i) {
            bad |= ((unsigned)q[i].x ^ tgt);
            bad |= ((unsigned)q[i].y ^ tgt);
            bad |= ((unsigned)q[i].z ^ tgt);
            bad |= ((unsigned)q[i].w ^ tgt);
          }
        }
        if (__all(ln >= 8 || (bad & 0xffffu) == 0u)) break;
        if (++guard > SPIN_CAP) break;        // deadlock escape (never legit)
      }
    }
    __builtin_amdgcn_sched_barrier(0);

    // ---- unpack + 64 MFMAs (8 independent n-tile chains) ----
    f32x4 acc[8];
#pragma unroll
    for (int i = 0; i < 8; ++i) acc[i] = (f32x4){0.f,0.f,0.f,0.f};
#pragma unroll
    for (int kt = 0; kt < 8; ++kt) {
      i32x4 lo = q[2 * kt], hi = q[2 * kt + 1];
      unsigned d0 = ((unsigned)lo.x >> 16) | ((unsigned)lo.y & 0xffff0000u);
      unsigned d1 = ((unsigned)lo.z >> 16) | ((unsigned)lo.w & 0xffff0000u);
      unsigned d2 = ((unsigned)hi.x >> 16) | ((unsigned)hi.y & 0xffff0000u);
      unsigned d3 = ((unsigned)hi.z >> 16) | ((unsigned)hi.w & 0xffff0000u);
      union { i32x4 i; bf16x8 h; } u2;
      u2.i = (i32x4){ (int)d0, (int)d1, (int)d2, (int)d3 };
#pragma unroll
      for (int nt = 0; nt < 8; ++nt)
        acc[nt] = __builtin_amdgcn_mfma_f32_16x16x32_bf16(u2.h, bw[nt][kt], acc[nt], 0, 0, 0);
    }

    // ---- partials to LDS: m=kg*4+rr (sample, keep m<8), n=nt*16+ln ----
#pragma unroll
    for (int nt = 0; nt < 8; ++nt) {
      if (kg < 2) {
#pragma unroll
        for (int rr = 0; rr < 4; ++rr)
          gatesm[(w * 8 + kg * 4 + rr) * 128 + nt * 16 + ln] = acc[nt][rr];
      }
    }
    __syncthreads();

    // ---- elementwise cell update: thread (s,u) ----
    float g0 = prv.x, g1 = prv.y, g2 = prv.z, g3 = prv.w;
#pragma unroll
    for (int ww = 0; ww < 4; ++ww) {
      const float* gm = gatesm + (ww * 8 + s) * 128 + u;
      g0 += gm[0];     // gate i: localrow u
      g1 += gm[32];    // gate f
      g2 += gm[64];    // gate g
      g3 += gm[96];    // gate o
    }
    float ii = __builtin_amdgcn_rcpf(1.f + __expf(-g0));
    float ff = __builtin_amdgcn_rcpf(1.f + __expf(-g1));
    float gt = 1.f - 2.f * __builtin_amdgcn_rcpf(1.f + __expf(2.f * g2));
    float oo = __builtin_amdgcn_rcpf(1.f + __expf(-g3));
    c = ff * c + ii * gt;
    float hv = oo * (1.f - 2.f * __builtin_amdgcn_rcpf(1.f + __expf(2.f * c)));

    // ---- publish version t+2 + outs[t+1] ----
    {
      unsigned short hb = f2bf(hv);
      unsigned word = ((unsigned)hb << 16) | ((unsigned)(t + 2) & 0xffffu);
      unsigned* hp = hcomm + ((size_t)((t + 2) & 1)) * 65536 + (size_t)sg * 1024 + ug;
      asm volatile("global_store_dword %0, %1, off sc0 sc1" :: "v"(hp), "v"(word) : "memory");
      outs[(size_t)(t + 1) * 65536 + (size_t)sg * 1024 + ug] = hb;
    }
    __syncthreads();   // WAR guard for gatesm across steps
  }
}

// ---------------- decode: out[32768,256] = outs_bf @ W_dec^T + b_dec ----------------
__global__ __launch_bounds__(256) void decode_kernel(
    const unsigned short* __restrict__ A,    // outs bf16 [32768][1024]
    const unsigned short* __restrict__ Wd,   // W_dec bf16 [256][1024]
    const float* __restrict__ bdec,
    float* __restrict__ out)                 // [32768][256]
{
  __shared__ __align__(16) unsigned char Asm[64 * 128];
  const int tid = threadIdx.x;
  const int w = tid >> 6;
  const int lane = tid & 63;
  const int ln = lane & 15, kg = lane >> 4;
  const int m0 = blockIdx.x * 64;
  const int nb = w * 64;                     // 4 waves cover N=256
  const int srow = tid >> 2, skq = tid & 3;

  f32x4 acc[4][4];
  for (int a = 0; a < 4; ++a) for (int b = 0; b < 4; ++b) acc[a][b] = (f32x4){0.f,0.f,0.f,0.f};

  for (int kc = 0; kc < 16; ++kc) {          // K=1024 in chunks of 64
    {
      const unsigned short* src = A + (m0 + srow) * 1024 + kc * 64 + skq * 16;
      unsigned base = (unsigned)(srow * 128 + skq * 32);
      unsigned sw = (unsigned)((srow & 7) << 4);
      *(i32x4*)(Asm + ((base) ^ sw))      = *(const i32x4*)(src);
      *(i32x4*)(Asm + ((base + 16) ^ sw)) = *(const i32x4*)(src + 8);
    }
    __syncthreads();
    for (int kk = 0; kk < 2; ++kk) {
      bf16x8 afr[4];
      for (int mi = 0; mi < 4; ++mi) {
        int row = mi * 16 + ln;
        unsigned off = (unsigned)(row * 128 + (kk * 32 + kg * 8) * 2);
        afr[mi] = *(const bf16x8*)(Asm + (off ^ ((unsigned)(row & 7) << 4)));
      }
      for (int ni = 0; ni < 4; ++ni) {
        const unsigned short* bp = Wd + (nb + ni * 16 + ln) * 1024 + kc * 64 + kk * 32 + kg * 8;
        bf16x8 bfr = *(const bf16x8*)bp;
        for (int mi = 0; mi < 4; ++mi)
          acc[mi][ni] = __builtin_amdgcn_mfma_f32_16x16x32_bf16(afr[mi], bfr, acc[mi][ni], 0, 0, 0);
      }
    }
    __syncthreads();
  }
  for (int ni = 0; ni < 4; ++ni) {
    int nn = nb + ni * 16 + ln;
    float bd = bdec[nn];
    for (int mi = 0; mi < 4; ++mi) {
      int mr = m0 + mi * 16 + kg * 4;
      for (int r = 0; r < 4; ++r)
        out[(mr + r) * 256 + nn] = acc[mi][ni][r] + bd;
    }
  }
}

// ---------------- host ----------------
extern "C" void kernel_launch(void* const* d_in, const int* in_sizes, int n_in,
                              void* d_out, int out_size, void* d_ws, size_t ws_size,
                              hipStream_t stream) {
  const int*   ints = (const int*)  d_in[0];
  const float* enc  = (const float*)d_in[1];
  const float* out0 = (const float*)d_in[2];
  const float* mem0 = (const float*)d_in[3];
  const float* Wih  = (const float*)d_in[4];
  const float* Whh  = (const float*)d_in[5];
  const float* bih  = (const float*)d_in[6];
  const float* bhh  = (const float*)d_in[7];
  const float* Wdec = (const float*)d_in[8];
  const float* bdec = (const float*)d_in[9];
  float* out = (float*)d_out;

  char* ws = (char*)d_ws;
  size_t off = 0;
  auto alloc = [&](size_t bytes) { char* p = ws + off; off += (bytes + 255) & ~(size_t)255; return p; };
  unsigned short* Whh_bf  = (unsigned short*)alloc(4096ull * 1024 * 2);     // 8 MB
  unsigned short* enc_bf  = (unsigned short*)alloc(256ull * 512 * 2);
  unsigned short* Wih_bf  = (unsigned short*)alloc(4096ull * 512 * 2);      // 4 MB
  unsigned short* Wdec_bf = (unsigned short*)alloc(256ull * 1024 * 2);
  float*          proj    = (float*)alloc(256ull * 4096 * 4);               // 4 MB packed
  unsigned short* outs_bf = (unsigned short*)alloc(512ull * 64 * 1024 * 2); // 64 MB
  unsigned int*   hcomm   = (unsigned int*)alloc(2ull * 64 * 1024 * 4);     // 512 KB
  // total ~81 MB of ws

  // Zero the tag ring every launch (first call sees recycled ws garbage;
  // tag 0 never matches any target).
  hipMemsetAsync(hcomm, 0, 2ull * 64 * 1024 * 4, stream);

  cvt_bf16<<<512, 256, 0, stream>>>(Whh,  Whh_bf,  4096 * 1024 / 4);
  cvt_bf16<<<64,  256, 0, stream>>>(enc,  enc_bf,  256 * 512 / 4);
  cvt_bf16<<<256, 256, 0, stream>>>(Wih,  Wih_bf,  4096 * 512 / 4);
  cvt_bf16<<<64,  256, 0, stream>>>(Wdec, Wdec_bf, 256 * 1024 / 4);

  proj_kernel<<<dim3(4, 16), 256, 0, stream>>>(enc_bf, Wih_bf, bih, bhh, proj);

  {
    const unsigned short* a0 = Whh_bf;
    const float* a1 = proj;
    const int* a2 = ints;
    const float* a3 = out0;
    const float* a4 = mem0;
    unsigned int* a5 = hcomm;
    unsigned short* a6 = outs_bf;
    void* args[] = { &a0, &a1, &a2, &a3, &a4, &a5, &a6 };
    hipError_t e = hipLaunchCooperativeKernel((const void*)scan_kernel,
                                              dim3(256), dim3(256), args, 0, stream);
    if (e != hipSuccess) {
      // fallback: plain launch; ~400 VGPR -> 1 blk/CU, 256 blocks co-resident
      scan_kernel<<<256, 256, 0, stream>>>(Whh_bf, proj, ints, out0, mem0,
                                           hcomm, outs_bf);
    }
  }

  decode_kernel<<<512, 256, 0, stream>>>(outs_bf, Wdec_bf, bdec, out);
}

// Round 10
// 1709.125 us; speedup vs baseline: 1.3945x; 1.0789x over previous
//
#include <hip/hip_runtime.h>

// LSTMCharacterPredictor — round 10: 8-wave scan, W truly VGPR-resident.
// T=512 B=64 E=512 H=1024 V=256.
// R9 post-mortem: asm pin can't stop SPILLING (VGPR stuck at 196 with 256
// declared W regs) -> shrink per-wave W footprint instead. 512 thr/block
// (8 waves), wave w owns K-slice [w*128,+128): bw[8][4]=128 VGPRs + q 32 +
// acc 32 + misc ~= 230 peak < 256-cap (launch_bounds(512,2), 1 blk/CU).
// Topology/protocol identical to R8: 8 groups x 32 blocks, tagged-h sc0sc1.

#define TT 512
#define BB 64
#define HH 1024
#define VV 256
#define EE 512
#define SPIN_CAP 16384

typedef __attribute__((ext_vector_type(8))) short bf16x8;
typedef __attribute__((ext_vector_type(4))) float f32x4;
typedef __attribute__((ext_vector_type(4))) int i32x4;
typedef __attribute__((ext_vector_type(4))) unsigned short u16x4;

static __device__ __forceinline__ unsigned short f2bf(float f) {
  union { float f; unsigned u; } x; x.f = f;
  unsigned r = x.u + 0x7fffu + ((x.u >> 16) & 1u);   // RNE
  return (unsigned short)(r >> 16);
}

// ---------------- f32 -> bf16 convert (vectorized) ----------------
__global__ void cvt_bf16(const float* __restrict__ s, unsigned short* __restrict__ d, int n4) {
  int i = blockIdx.x * blockDim.x + threadIdx.x;
  int st = gridDim.x * blockDim.x;
  for (; i < n4; i += st) {
    f32x4 v = *(const f32x4*)(s + 4l * i);
    u16x4 o;
    o.x = f2bf(v.x); o.y = f2bf(v.y); o.z = f2bf(v.z); o.w = f2bf(v.w);
    *(u16x4*)(d + 4l * i) = o;
  }
}

// ------- proj packed: proj[v][unit][gate] = enc@W_ih^T + b_ih + b_hh -------
__global__ __launch_bounds__(256) void proj_kernel(
    const unsigned short* __restrict__ A,    // enc bf16 [256][512]
    const unsigned short* __restrict__ Wi,   // W_ih bf16 [4096][512]
    const float* __restrict__ bih, const float* __restrict__ bhh,
    float* __restrict__ proj)                // [256][1024][4] f32
{
  __shared__ __align__(16) unsigned char Asm[64 * 128];   // [64 m][64 k] bf16, swizzled
  const int tid = threadIdx.x;
  const int w = tid >> 6;
  const int lane = tid & 63;
  const int ln = lane & 15, kg = lane >> 4;
  const int m0 = blockIdx.x * 64;            // 4 blocks
  const int nb = blockIdx.y * 256 + w * 64;  // 16 blocks.y, wave owns 64 n
  const int srow = tid >> 2, skq = tid & 3;

  f32x4 acc[4][4];
  for (int a = 0; a < 4; ++a) for (int b = 0; b < 4; ++b) acc[a][b] = (f32x4){0.f,0.f,0.f,0.f};

  for (int kc = 0; kc < 8; ++kc) {           // K=512 in chunks of 64
    {
      const unsigned short* src = A + (m0 + srow) * 512 + kc * 64 + skq * 16;
      unsigned base = (unsigned)(srow * 128 + skq * 32);
      unsigned sw = (unsigned)((srow & 7) << 4);
      *(i32x4*)(Asm + ((base) ^ sw))      = *(const i32x4*)(src);
      *(i32x4*)(Asm + ((base + 16) ^ sw)) = *(const i32x4*)(src + 8);
    }
    __syncthreads();
    for (int kk = 0; kk < 2; ++kk) {
      bf16x8 afr[4];
      for (int mi = 0; mi < 4; ++mi) {
        int row = mi * 16 + ln;
        unsigned off = (unsigned)(row * 128 + (kk * 32 + kg * 8) * 2);
        afr[mi] = *(const bf16x8*)(Asm + (off ^ ((unsigned)(row & 7) << 4)));
      }
      for (int ni = 0; ni < 4; ++ni) {
        const unsigned short* bp = Wi + (nb + ni * 16 + ln) * 512 + kc * 64 + kk * 32 + kg * 8;
        bf16x8 bfr = *(const bf16x8*)bp;
        for (int mi = 0; mi < 4; ++mi)
          acc[mi][ni] = __builtin_amdgcn_mfma_f32_16x16x32_bf16(afr[mi], bfr, acc[mi][ni], 0, 0, 0);
      }
    }
    __syncthreads();
  }
  for (int ni = 0; ni < 4; ++ni) {
    int nn = nb + ni * 16 + ln;             // global gate-row = gi*1024 + unit
    int gi = nn >> 10, uu = nn & 1023;
    float bias = bih[nn] + bhh[nn];
    for (int mi = 0; mi < 4; ++mi) {
      int mr = m0 + mi * 16 + kg * 4;
      for (int r = 0; r < 4; ++r)
        proj[(size_t)(mr + r) * 4096 + uu * 4 + gi] = acc[mi][ni][r] + bias;
    }
  }
}

// ---------------- persistent LSTM scan (8 waves, W resident) ----------------
// group g=blk&7 owns samples [g*8,+8); slice r=blk>>3 owns units [r*32,+32).
// Wave w in [0,8): K-slice [w*128,+128) of the 128 local gate rows.
// bw[8 n-tiles][4 k-tiles] = 128 VGPRs. MFMA M=16: rows 0..7 real samples.
// hcomm[slot][sample][unit] = (bf16 h)<<16 | version, slot=version&1.
__global__ __launch_bounds__(512, 2) void scan_kernel(
    const unsigned short* __restrict__ Whh,   // bf16 [4096][1024]
    const float* __restrict__ proj,           // [256][1024][4] f32 packed
    const int* __restrict__ ints,             // [512][64]
    const float* __restrict__ h0v,            // output0 [1024]
    const float* __restrict__ c0v,            // memory0 [1024]
    unsigned int* __restrict__ hcomm,         // [2][64][1024] tagged u32
    unsigned short* __restrict__ outs)        // bf16 [512][64][1024] h history
{
  __shared__ float gatesm[8 * 8 * 128];       // [wave][sample(8)][localrow(128)] 32 KB

  const int tid = threadIdx.x;
  const int blk = blockIdx.x;
  const int g = blk & 7, r = blk >> 3;        // XCD-affine heuristic mapping
  const int w = tid >> 6, lane = tid & 63;
  const int ln = lane & 15, kg = lane >> 4;
  const int s = (tid & 255) >> 5, u = tid & 31;  // elementwise cell (tid<256)
  const int sg = g * 8 + s;
  const int ug = r * 32 + u;

  // W_hh B-frags: local gate-row lrow=nt*16+ln -> global row
  // (lrow>>5)*1024 + r*32 + (lrow&31); k = w*128 + kt*32 + kg*8 + [0,8).
  bf16x8 bw[8][4];
#pragma unroll
  for (int nt = 0; nt < 8; ++nt) {
    int lrow = nt * 16 + ln;
    int grow = (lrow >> 5) * 1024 + r * 32 + (lrow & 31);
    const unsigned short* wp = Whh + (size_t)grow * 1024 + w * 128 + kg * 8;
#pragma unroll
    for (int kt = 0; kt < 4; ++kt)
      bw[nt][kt] = *(const bf16x8*)(wp + kt * 32);
  }
  // pin against rematerialization (spill headroom now exists: ~230 < 256)
#pragma unroll
  for (int nt = 0; nt < 8; ++nt)
#pragma unroll
    for (int kt = 0; kt < 4; ++kt)
      asm volatile("" : "+v"(bw[nt][kt]));

  float c = (tid < 256) ? c0v[ug] : 0.f;

  // publish version 1 (= h0) into slot 1; outs[0]  (tid<256: one per (s,u))
  if (tid < 256) {
    unsigned short hb = f2bf(h0v[ug]);
    unsigned word = ((unsigned)hb << 16) | 1u;
    unsigned* hp = hcomm + 65536 + (size_t)sg * 1024 + ug;
    asm volatile("global_store_dword %0, %1, off sc0 sc1" :: "v"(hp), "v"(word) : "memory");
    outs[(size_t)sg * 1024 + ug] = hb;
  }

  i32x4 q[8];
#pragma unroll
  for (int i = 0; i < 8; ++i) q[i] = (i32x4){0, 0, 0, 0};

  for (int t = 0; t < TT - 1; ++t) {
    // ---- prefetch packed proj (tid<256; poll's vmcnt drains it) ----
    f32x4 prv = (f32x4){0.f,0.f,0.f,0.f};
    if (tid < 256) {
      int vocab = ints[t * 64 + sg];
      const float* pp = proj + (size_t)vocab * 4096 + ug * 4;
      asm volatile("global_load_dwordx4 %0, %1, off" : "=v"(prv) : "v"(pp) : "memory");
    }

    // ---- poll A-rows (lanes ln<8 = real samples; ln>=8 pads keep q=0) ----
    const unsigned* ab = hcomm + ((size_t)((t + 1) & 1)) * 65536
                       + (size_t)(g * 8 + (ln & 7)) * 1024 + w * 128 + kg * 8;
    unsigned tgt = (unsigned)(t + 1);
    {
      int guard = 0;
      while (true) {
        if (ln < 8) {
#define LQ(i, off_lit) \
          asm volatile("global_load_dwordx4 %0, %1, off offset:" off_lit " sc0 sc1" \
                       : "=v"(q[i]) : "v"(ab) : "memory")
          LQ(0, "0");   LQ(1, "16");  LQ(2, "128"); LQ(3, "144");
          LQ(4, "256"); LQ(5, "272"); LQ(6, "384"); LQ(7, "400");
#undef LQ
        }
        asm volatile("s_waitcnt vmcnt(0)" ::: "memory");
        __builtin_amdgcn_sched_barrier(0);    // rule 18: keep checks after wait
        unsigned bad = 0;
        if (ln < 8) {
#pragma unroll
          for (int i = 0; i < 8; ++i) {
            bad |= ((unsigned)q[i].x ^ tgt);
            bad |= ((unsigned)q[i].y ^ tgt);
            bad |= ((unsigned)q[i].z ^ tgt);
            bad |= ((unsigned)q[i].w ^ tgt);
          }
        }
        if (__all(ln >= 8 || (bad & 0xffffu) == 0u)) break;
        if (++guard > SPIN_CAP) break;        // deadlock escape (never legit)
      }
    }
    __builtin_amdgcn_sched_barrier(0);

    // ---- unpack + 32 MFMAs/wave (8 independent n-tile chains) ----
    f32x4 acc[8];
#pragma unroll
    for (int i = 0; i < 8; ++i) acc[i] = (f32x4){0.f,0.f,0.f,0.f};
#pragma unroll
    for (int kt = 0; kt < 4; ++kt) {
      i32x4 lo = q[2 * kt], hi = q[2 * kt + 1];
      unsigned d0 = ((unsigned)lo.x >> 16) | ((unsigned)lo.y & 0xffff0000u);
      unsigned d1 = ((unsigned)lo.z >> 16) | ((unsigned)lo.w & 0xffff0000u);
      unsigned d2 = ((unsigned)hi.x >> 16) | ((unsigned)hi.y & 0xffff0000u);
      unsigned d3 = ((unsigned)hi.z >> 16) | ((unsigned)hi.w & 0xffff0000u);
      union { i32x4 i; bf16x8 h; } u2;
      u2.i = (i32x4){ (int)d0, (int)d1, (int)d2, (int)d3 };
#pragma unroll
      for (int nt = 0; nt < 8; ++nt)
        acc[nt] = __builtin_amdgcn_mfma_f32_16x16x32_bf16(u2.h, bw[nt][kt], acc[nt], 0, 0, 0);
    }

    // ---- partials to LDS: m=kg*4+rr (sample, keep m<8), n=nt*16+ln ----
#pragma unroll
    for (int nt = 0; nt < 8; ++nt) {
      if (kg < 2) {
#pragma unroll
        for (int rr = 0; rr < 4; ++rr)
          gatesm[(w * 8 + kg * 4 + rr) * 128 + nt * 16 + ln] = acc[nt][rr];
      }
    }
    __syncthreads();

    // ---- elementwise cell update: tid<256, thread (s,u) ----
    if (tid < 256) {
      float g0 = prv.x, g1 = prv.y, g2 = prv.z, g3 = prv.w;
#pragma unroll
      for (int ww = 0; ww < 8; ++ww) {
        const float* gm = gatesm + (ww * 8 + s) * 128 + u;
        g0 += gm[0];     // gate i: localrow u
        g1 += gm[32];    // gate f
        g2 += gm[64];    // gate g
        g3 += gm[96];    // gate o
      }
      float ii = __builtin_amdgcn_rcpf(1.f + __expf(-g0));
      float ff = __builtin_amdgcn_rcpf(1.f + __expf(-g1));
      float gt = 1.f - 2.f * __builtin_amdgcn_rcpf(1.f + __expf(2.f * g2));
      float oo = __builtin_amdgcn_rcpf(1.f + __expf(-g3));
      c = ff * c + ii * gt;
      float hv = oo * (1.f - 2.f * __builtin_amdgcn_rcpf(1.f + __expf(2.f * c)));

      // ---- publish version t+2 + outs[t+1] ----
      unsigned short hb = f2bf(hv);
      unsigned word = ((unsigned)hb << 16) | ((unsigned)(t + 2) & 0xffffu);
      unsigned* hp = hcomm + ((size_t)((t + 2) & 1)) * 65536 + (size_t)sg * 1024 + ug;
      asm volatile("global_store_dword %0, %1, off sc0 sc1" :: "v"(hp), "v"(word) : "memory");
      outs[(size_t)(t + 1) * 65536 + (size_t)sg * 1024 + ug] = hb;
    }
    __syncthreads();   // WAR guard for gatesm across steps
  }
}

// ---------------- decode: out[32768,256] = outs_bf @ W_dec^T + b_dec ----------------
__global__ __launch_bounds__(256) void decode_kernel(
    const unsigned short* __restrict__ A,    // outs bf16 [32768][1024]
    const unsigned short* __restrict__ Wd,   // W_dec bf16 [256][1024]
    const float* __restrict__ bdec,
    float* __restrict__ out)                 // [32768][256]
{
  __shared__ __align__(16) unsigned char Asm[64 * 128];
  const int tid = threadIdx.x;
  const int w = tid >> 6;
  const int lane = tid & 63;
  const int ln = lane & 15, kg = lane >> 4;
  const int m0 = blockIdx.x * 64;
  const int nb = w * 64;                     // 4 waves cover N=256
  const int srow = tid >> 2, skq = tid & 3;

  f32x4 acc[4][4];
  for (int a = 0; a < 4; ++a) for (int b = 0; b < 4; ++b) acc[a][b] = (f32x4){0.f,0.f,0.f,0.f};

  for (int kc = 0; kc < 16; ++kc) {          // K=1024 in chunks of 64
    {
      const unsigned short* src = A + (m0 + srow) * 1024 + kc * 64 + skq * 16;
      unsigned base = (unsigned)(srow * 128 + skq * 32);
      unsigned sw = (unsigned)((srow & 7) << 4);
      *(i32x4*)(Asm + ((base) ^ sw))      = *(const i32x4*)(src);
      *(i32x4*)(Asm + ((base + 16) ^ sw)) = *(const i32x4*)(src + 8);
    }
    __syncthreads();
    for (int kk = 0; kk < 2; ++kk) {
      bf16x8 afr[4];
      for (int mi = 0; mi < 4; ++mi) {
        int row = mi * 16 + ln;
        unsigned off = (unsigned)(row * 128 + (kk * 32 + kg * 8) * 2);
        afr[mi] = *(const bf16x8*)(Asm + (off ^ ((unsigned)(row & 7) << 4)));
      }
      for (int ni = 0; ni < 4; ++ni) {
        const unsigned short* bp = Wd + (nb + ni * 16 + ln) * 1024 + kc * 64 + kk * 32 + kg * 8;
        bf16x8 bfr = *(const bf16x8*)bp;
        for (int mi = 0; mi < 4; ++mi)
          acc[mi][ni] = __builtin_amdgcn_mfma_f32_16x16x32_bf16(afr[mi], bfr, acc[mi][ni], 0, 0, 0);
      }
    }
    __syncthreads();
  }
  for (int ni = 0; ni < 4; ++ni) {
    int nn = nb + ni * 16 + ln;
    float bd = bdec[nn];
    for (int mi = 0; mi < 4; ++mi) {
      int mr = m0 + mi * 16 + kg * 4;
      for (int r = 0; r < 4; ++r)
        out[(mr + r) * 256 + nn] = acc[mi][ni][r] + bd;
    }
  }
}

// ---------------- host ----------------
extern "C" void kernel_launch(void* const* d_in, const int* in_sizes, int n_in,
                              void* d_out, int out_size, void* d_ws, size_t ws_size,
                              hipStream_t stream) {
  const int*   ints = (const int*)  d_in[0];
  const float* enc  = (const float*)d_in[1];
  const float* out0 = (const float*)d_in[2];
  const float* mem0 = (const float*)d_in[3];
  const float* Wih  = (const float*)d_in[4];
  const float* Whh  = (const float*)d_in[5];
  const float* bih  = (const float*)d_in[6];
  const float* bhh  = (const float*)d_in[7];
  const float* Wdec = (const float*)d_in[8];
  const float* bdec = (const float*)d_in[9];
  float* out = (float*)d_out;

  char* ws = (char*)d_ws;
  size_t off = 0;
  auto alloc = [&](size_t bytes) { char* p = ws + off; off += (bytes + 255) & ~(size_t)255; return p; };
  unsigned short* Whh_bf  = (unsigned short*)alloc(4096ull * 1024 * 2);     // 8 MB
  unsigned short* enc_bf  = (unsigned short*)alloc(256ull * 512 * 2);
  unsigned short* Wih_bf  = (unsigned short*)alloc(4096ull * 512 * 2);      // 4 MB
  unsigned short* Wdec_bf = (unsigned short*)alloc(256ull * 1024 * 2);
  float*          proj    = (float*)alloc(256ull * 4096 * 4);               // 4 MB packed
  unsigned short* outs_bf = (unsigned short*)alloc(512ull * 64 * 1024 * 2); // 64 MB
  unsigned int*   hcomm   = (unsigned int*)alloc(2ull * 64 * 1024 * 4);     // 512 KB
  // total ~81 MB of ws

  // Zero the tag ring every launch (first call sees recycled ws garbage;
  // tag 0 never matches any target).
  hipMemsetAsync(hcomm, 0, 2ull * 64 * 1024 * 4, stream);

  cvt_bf16<<<512, 256, 0, stream>>>(Whh,  Whh_bf,  4096 * 1024 / 4);
  cvt_bf16<<<64,  256, 0, stream>>>(enc,  enc_bf,  256 * 512 / 4);
  cvt_bf16<<<256, 256, 0, stream>>>(Wih,  Wih_bf,  4096 * 512 / 4);
  cvt_bf16<<<64,  256, 0, stream>>>(Wdec, Wdec_bf, 256 * 1024 / 4);

  proj_kernel<<<dim3(4, 16), 256, 0, stream>>>(enc_bf, Wih_bf, bih, bhh, proj);

  {
    const unsigned short* a0 = Whh_bf;
    const float* a1 = proj;
    const int* a2 = ints;
    const float* a3 = out0;
    const float* a4 = mem0;
    unsigned int* a5 = hcomm;
    unsigned short* a6 = outs_bf;
    void* args[] = { &a0, &a1, &a2, &a3, &a4, &a5, &a6 };
    hipError_t e = hipLaunchCooperativeKernel((const void*)scan_kernel,
                                              dim3(256), dim3(512), args, 0, stream);
    if (e != hipSuccess) {
      // fallback: plain launch; 512 thr x ~250 VGPR -> 1 blk/CU, 256 co-resident
      scan_kernel<<<256, 512, 0, stream>>>(Whh_bf, proj, ints, out0, mem0,
                                           hcomm, outs_bf);
    }
  }

  decode_kernel<<<512, 256, 0, stream>>>(outs_bf, Wdec_bf, bdec, out);
}